// Round 1
// baseline (7031.789 us; speedup 1.0000x reference)
//
#include <hip/hip_runtime.h>
#include <math.h>

namespace {
constexpr int kB = 16;
constexpr int kV = 500000;
constexpr int kF = 1000000;
constexpr float kEps = 1e-6f;
}

// One thread per (b, f); f is the fast dimension so faces reads and area
// writes are coalesced. Vertex gathers are inherently random (cached by L2/L3;
// vertices footprint 96 MB < 256 MB L3). 9 fp32 HW atomics scatter the face
// normal into the per-vertex accumulator (d_out vectors region, pre-zeroed).
__global__ __launch_bounds__(256) void face_normals_kernel(
    const float* __restrict__ verts,   // [B][V][3]
    const int*   __restrict__ faces,   // [F][3]
    float*       __restrict__ vnorm,   // [B][V][3] accumulator (zeroed)
    float*       __restrict__ areas)   // [B][F]
{
    long long tid = (long long)blockIdx.x * blockDim.x + threadIdx.x;
    if (tid >= (long long)kB * kF) return;
    int f = (int)(tid % kF);
    int b = (int)(tid / kF);

    int i0 = faces[3 * f + 0];
    int i1 = faces[3 * f + 1];
    int i2 = faces[3 * f + 2];

    const float* vb = verts + (size_t)b * kV * 3;
    size_t o0 = 3 * (size_t)i0, o1 = 3 * (size_t)i1, o2 = 3 * (size_t)i2;

    float x0 = vb[o0 + 0], y0 = vb[o0 + 1], z0 = vb[o0 + 2];
    float x1 = vb[o1 + 0], y1 = vb[o1 + 1], z1 = vb[o1 + 2];
    float x2 = vb[o2 + 0], y2 = vb[o2 + 1], z2 = vb[o2 + 2];

    // e1 = v1 - v0, e2 = v2 - v1, n = cross(e1, e2)
    float e1x = x1 - x0, e1y = y1 - y0, e1z = z1 - z0;
    float e2x = x2 - x1, e2y = y2 - y1, e2z = z2 - z1;
    float nx = e1y * e2z - e1z * e2y;
    float ny = e1z * e2x - e1x * e2z;
    float nz = e1x * e2y - e1y * e2x;

    float* vn = vnorm + (size_t)b * kV * 3;
    unsafeAtomicAdd(&vn[o0 + 0], nx);
    unsafeAtomicAdd(&vn[o0 + 1], ny);
    unsafeAtomicAdd(&vn[o0 + 2], nz);
    unsafeAtomicAdd(&vn[o1 + 0], nx);
    unsafeAtomicAdd(&vn[o1 + 1], ny);
    unsafeAtomicAdd(&vn[o1 + 2], nz);
    unsafeAtomicAdd(&vn[o2 + 0], nx);
    unsafeAtomicAdd(&vn[o2 + 1], ny);
    unsafeAtomicAdd(&vn[o2 + 2], nz);

    areas[(size_t)b * kF + f] = 0.5f * sqrtf(nx * nx + ny * ny + nz * nz);
}

// One thread per (b, v): normalize the accumulated vertex normal in place.
__global__ __launch_bounds__(256) void normalize_kernel(
    float* __restrict__ vnorm)   // [B][V][3], in/out
{
    long long tid = (long long)blockIdx.x * blockDim.x + threadIdx.x;
    if (tid >= (long long)kB * kV) return;
    size_t o = 3 * (size_t)tid;
    float x = vnorm[o + 0];
    float y = vnorm[o + 1];
    float z = vnorm[o + 2];
    float n = sqrtf(x * x + y * y + z * z);
    float inv = 1.0f / fmaxf(n, kEps);
    vnorm[o + 0] = x * inv;
    vnorm[o + 1] = y * inv;
    vnorm[o + 2] = z * inv;
}

extern "C" void kernel_launch(void* const* d_in, const int* in_sizes, int n_in,
                              void* d_out, int out_size, void* d_ws, size_t ws_size,
                              hipStream_t stream) {
    const float* verts = (const float*)d_in[0];
    const int*   faces = (const int*)d_in[1];

    float* out   = (float*)d_out;
    float* vecs  = out;                               // B*V*3 floats
    float* areas = out + (size_t)kB * kV * 3;         // B*F floats

    // Zero the accumulator region (we accumulate into the output directly).
    hipMemsetAsync(vecs, 0, (size_t)kB * kV * 3 * sizeof(float), stream);

    long long nface_work = (long long)kB * kF;
    int blk = 256;
    int grid_f = (int)((nface_work + blk - 1) / blk);
    face_normals_kernel<<<grid_f, blk, 0, stream>>>(verts, faces, vecs, areas);

    long long nvert_work = (long long)kB * kV;
    int grid_v = (int)((nvert_work + blk - 1) / blk);
    normalize_kernel<<<grid_v, blk, 0, stream>>>(vecs);
}

// Round 3
// 3006.112 us; speedup vs baseline: 2.3392x; 2.3392x over previous
//
#include <hip/hip_runtime.h>
#include <math.h>

namespace {
constexpr int kB = 16;
constexpr int kV = 500000;
constexpr int kF = 1000000;
constexpr float kEps = 1e-6f;
constexpr int kNB = (kV + 255) / 256;   // 1954
}

// a*b - c*d with contraction disabled: for degenerate faces (i0==i2, e2==-e1)
// both products round identically and cancel EXACTLY, matching numpy. FMA
// contraction would leave ~ulp noise that normalization amplifies to O(1).
__device__ __forceinline__ float cross_comp(float a, float b, float c, float d) {
    return __fsub_rn(__fmul_rn(a, b), __fmul_rn(c, d));
}

// ---------- CSR build (bitwise-deterministic end state) ----------

__global__ __launch_bounds__(256) void zero_count_kernel(int* __restrict__ count) {
    int i = blockIdx.x * 256 + threadIdx.x;
    if (i < kV) count[i] = 0;
}

__global__ __launch_bounds__(256) void count_kernel(
    const int* __restrict__ faces, int* __restrict__ count)
{
    int i = blockIdx.x * 256 + threadIdx.x;
    if (i >= 3 * kF) return;
    atomicAdd(&count[faces[i]], 1);   // int adds commute exactly -> deterministic
}

__device__ __forceinline__ int block_incl_scan256(int x, int* lds) {
    int lane = threadIdx.x & 63;
    int wave = threadIdx.x >> 6;
    for (int d = 1; d < 64; d <<= 1) {
        int y = __shfl_up(x, d, 64);
        if (lane >= d) x += y;
    }
    if (lane == 63) lds[wave] = x;
    __syncthreads();
    int add = 0;
    for (int w = 0; w < wave; ++w) add += lds[w];
    __syncthreads();
    return x + add;
}

__global__ __launch_bounds__(256) void scan_block_kernel(
    const int* __restrict__ count, int* __restrict__ offs,
    int* __restrict__ blockSums)
{
    __shared__ int lds[4];
    int i = blockIdx.x * 256 + threadIdx.x;
    int x = (i < kV) ? count[i] : 0;
    int incl = block_incl_scan256(x, lds);
    if (i < kV) offs[i] = incl - x;
    if (threadIdx.x == 255) blockSums[blockIdx.x] = incl;
}

__global__ __launch_bounds__(256) void scan_sums_kernel(int* __restrict__ blockSums) {
    __shared__ int lds[4];
    __shared__ int carry;
    if (threadIdx.x == 0) carry = 0;
    __syncthreads();
    for (int base = 0; base < kNB; base += 256) {
        int i = base + threadIdx.x;
        int x = (i < kNB) ? blockSums[i] : 0;
        int incl = block_incl_scan256(x, lds);
        int c = carry;
        __syncthreads();
        if (i < kNB) blockSums[i] = incl - x + c;
        if (threadIdx.x == 255) carry = c + incl;
        __syncthreads();
    }
}

__global__ __launch_bounds__(256) void add_offsets_kernel(
    int* __restrict__ offs, const int* __restrict__ blockSums)
{
    int i = blockIdx.x * 256 + threadIdx.x;
    if (i < kV) offs[i] += blockSums[i >> 8];
    if (i == kV) offs[kV] = 3 * kF;
}

__global__ __launch_bounds__(256) void fill_adj_kernel(
    const int* __restrict__ faces, const int* __restrict__ offs,
    int* __restrict__ count, int* __restrict__ adj)
{
    int i = blockIdx.x * 256 + threadIdx.x;
    if (i >= 3 * kF) return;
    int v = faces[i];
    int f = i / 3;
    int old = atomicSub(&count[v], 1);        // slot order nondeterministic...
    adj[offs[v] + old - 1] = f;
}

// ...so canonicalize: in-place insertion sort of each row (avg deg 6). After
// this, adj is bitwise deterministic, hence all downstream fp sums are too.
__global__ __launch_bounds__(256) void sort_rows_kernel(
    const int* __restrict__ offs, int* __restrict__ adj)
{
    int v = blockIdx.x * 256 + threadIdx.x;
    if (v >= kV) return;
    int s = offs[v], e = offs[v + 1];
    for (int i = s + 1; i < e; ++i) {
        int key = adj[i];
        int j = i - 1;
        while (j >= s && adj[j] > key) { adj[j + 1] = adj[j]; --j; }
        adj[j + 1] = key;
    }
}

// ---------- outputs (batch-amortized) ----------

// One thread per face; loops over the 16 batches. Face read once; per-b area
// writes are coalesced (lane = f).
__global__ __launch_bounds__(256) void area_kernel(
    const float* __restrict__ verts, const int* __restrict__ faces,
    float* __restrict__ areas)
{
    int f = blockIdx.x * 256 + threadIdx.x;
    if (f >= kF) return;
    int i0 = faces[3 * f + 0];
    int i1 = faces[3 * f + 1];
    int i2 = faces[3 * f + 2];
    size_t o0 = 3 * (size_t)i0, o1 = 3 * (size_t)i1, o2 = 3 * (size_t)i2;
#pragma unroll
    for (int b = 0; b < kB; ++b) {
        const float* vb = verts + (size_t)b * kV * 3;
        float x0 = vb[o0], y0 = vb[o0 + 1], z0 = vb[o0 + 2];
        float x1 = vb[o1], y1 = vb[o1 + 1], z1 = vb[o1 + 2];
        float x2 = vb[o2], y2 = vb[o2 + 1], z2 = vb[o2 + 2];
        float e1x = x1 - x0, e1y = y1 - y0, e1z = z1 - z0;
        float e2x = x2 - x1, e2y = y2 - y1, e2z = z2 - z1;
        float nx = cross_comp(e1y, e2z, e1z, e2y);
        float ny = cross_comp(e1z, e2x, e1x, e2z);
        float nz = cross_comp(e1x, e2y, e1y, e2x);
        areas[(size_t)b * kF + f] = 0.5f * sqrtf(nx * nx + ny * ny + nz * nz);
    }
}

// One thread per vertex; 48 fp32 accumulators (fully unrolled b -> registers).
// Row (sorted) read once; faces read once per incident face; vertex gathers
// are 48 independent loads per face -> deep MLP against L2/L3 latency.
__global__ __launch_bounds__(256) void gather_normalize_kernel(
    const float* __restrict__ verts, const int* __restrict__ faces,
    const int* __restrict__ offs, const int* __restrict__ adj,
    float* __restrict__ out)
{
    int v = blockIdx.x * 256 + threadIdx.x;
    if (v >= kV) return;
    int s = offs[v], e = offs[v + 1];

    float ax[kB], ay[kB], az[kB];
#pragma unroll
    for (int b = 0; b < kB; ++b) { ax[b] = 0.f; ay[b] = 0.f; az[b] = 0.f; }

    for (int j = s; j < e; ++j) {
        int f = adj[j];
        int i0 = faces[3 * f + 0];
        int i1 = faces[3 * f + 1];
        int i2 = faces[3 * f + 2];
        size_t o0 = 3 * (size_t)i0, o1 = 3 * (size_t)i1, o2 = 3 * (size_t)i2;
#pragma unroll
        for (int b = 0; b < kB; ++b) {
            const float* vb = verts + (size_t)b * kV * 3;
            float x0 = vb[o0], y0 = vb[o0 + 1], z0 = vb[o0 + 2];
            float x1 = vb[o1], y1 = vb[o1 + 1], z1 = vb[o1 + 2];
            float x2 = vb[o2], y2 = vb[o2 + 1], z2 = vb[o2 + 2];
            float e1x = x1 - x0, e1y = y1 - y0, e1z = z1 - z0;
            float e2x = x2 - x1, e2y = y2 - y1, e2z = z2 - z1;
            ax[b] += cross_comp(e1y, e2z, e1z, e2y);
            ay[b] += cross_comp(e1z, e2x, e1x, e2z);
            az[b] += cross_comp(e1x, e2y, e1y, e2x);
        }
    }

#pragma unroll
    for (int b = 0; b < kB; ++b) {
        float n = sqrtf(ax[b] * ax[b] + ay[b] * ay[b] + az[b] * az[b]);
        float inv = 1.0f / fmaxf(n, kEps);
        size_t o = ((size_t)b * kV + v) * 3;
        out[o + 0] = ax[b] * inv;
        out[o + 1] = ay[b] * inv;
        out[o + 2] = az[b] * inv;
    }
}

// ---------- fallback (R1 path, used only if ws too small) ----------

__global__ __launch_bounds__(256) void face_normals_atomic_kernel(
    const float* __restrict__ verts, const int* __restrict__ faces,
    float* __restrict__ vnorm, float* __restrict__ areas)
{
    long long tid = (long long)blockIdx.x * blockDim.x + threadIdx.x;
    if (tid >= (long long)kB * kF) return;
    int f = (int)(tid % kF);
    int b = (int)(tid / kF);
    int i0 = faces[3 * f + 0], i1 = faces[3 * f + 1], i2 = faces[3 * f + 2];
    const float* vb = verts + (size_t)b * kV * 3;
    size_t o0 = 3 * (size_t)i0, o1 = 3 * (size_t)i1, o2 = 3 * (size_t)i2;
    float x0 = vb[o0], y0 = vb[o0 + 1], z0 = vb[o0 + 2];
    float x1 = vb[o1], y1 = vb[o1 + 1], z1 = vb[o1 + 2];
    float x2 = vb[o2], y2 = vb[o2 + 1], z2 = vb[o2 + 2];
    float e1x = x1 - x0, e1y = y1 - y0, e1z = z1 - z0;
    float e2x = x2 - x1, e2y = y2 - y1, e2z = z2 - z1;
    float nx = cross_comp(e1y, e2z, e1z, e2y);
    float ny = cross_comp(e1z, e2x, e1x, e2z);
    float nz = cross_comp(e1x, e2y, e1y, e2x);
    float* vn = vnorm + (size_t)b * kV * 3;
    unsafeAtomicAdd(&vn[o0 + 0], nx); unsafeAtomicAdd(&vn[o0 + 1], ny); unsafeAtomicAdd(&vn[o0 + 2], nz);
    unsafeAtomicAdd(&vn[o1 + 0], nx); unsafeAtomicAdd(&vn[o1 + 1], ny); unsafeAtomicAdd(&vn[o1 + 2], nz);
    unsafeAtomicAdd(&vn[o2 + 0], nx); unsafeAtomicAdd(&vn[o2 + 1], ny); unsafeAtomicAdd(&vn[o2 + 2], nz);
    areas[(size_t)b * kF + f] = 0.5f * sqrtf(nx * nx + ny * ny + nz * nz);
}

__global__ __launch_bounds__(256) void normalize_inplace_kernel(float* __restrict__ vnorm) {
    long long tid = (long long)blockIdx.x * blockDim.x + threadIdx.x;
    if (tid >= (long long)kB * kV) return;
    size_t o = 3 * (size_t)tid;
    float x = vnorm[o], y = vnorm[o + 1], z = vnorm[o + 2];
    float n = sqrtf(x * x + y * y + z * z);
    float inv = 1.0f / fmaxf(n, kEps);
    vnorm[o] = x * inv; vnorm[o + 1] = y * inv; vnorm[o + 2] = z * inv;
}

// ---------- launch ----------

extern "C" void kernel_launch(void* const* d_in, const int* in_sizes, int n_in,
                              void* d_out, int out_size, void* d_ws, size_t ws_size,
                              hipStream_t stream) {
    const float* verts = (const float*)d_in[0];
    const int*   faces = (const int*)d_in[1];

    float* out   = (float*)d_out;
    float* vecs  = out;                               // B*V*3
    float* areas = out + (size_t)kB * kV * 3;         // B*F

    size_t need_ints = (size_t)kV + (kV + 1) + kNB + 3 * (size_t)kF;
    if (ws_size < need_ints * sizeof(int)) {
        hipMemsetAsync(vecs, 0, (size_t)kB * kV * 3 * sizeof(float), stream);
        long long nf = (long long)kB * kF;
        face_normals_atomic_kernel<<<(int)((nf + 255) / 256), 256, 0, stream>>>(verts, faces, vecs, areas);
        long long nv = (long long)kB * kV;
        normalize_inplace_kernel<<<(int)((nv + 255) / 256), 256, 0, stream>>>(vecs);
        return;
    }

    int* count     = (int*)d_ws;           // [V]
    int* offs      = count + kV;           // [V+1]
    int* blockSums = offs + (kV + 1);      // [kNB]
    int* adj       = blockSums + kNB;      // [3F]

    int gInc = (3 * kF + 255) / 256;

    zero_count_kernel<<<kNB, 256, 0, stream>>>(count);
    count_kernel<<<gInc, 256, 0, stream>>>(faces, count);
    scan_block_kernel<<<kNB, 256, 0, stream>>>(count, offs, blockSums);
    scan_sums_kernel<<<1, 256, 0, stream>>>(blockSums);
    add_offsets_kernel<<<(kV + 1 + 255) / 256, 256, 0, stream>>>(offs, blockSums);
    fill_adj_kernel<<<gInc, 256, 0, stream>>>(faces, offs, count, adj);
    sort_rows_kernel<<<kNB, 256, 0, stream>>>(offs, adj);

    area_kernel<<<(kF + 255) / 256, 256, 0, stream>>>(verts, faces, areas);
    gather_normalize_kernel<<<kNB, 256, 0, stream>>>(verts, faces, offs, adj, vecs);
}

// Round 4
// 1055.531 us; speedup vs baseline: 6.6619x; 2.8480x over previous
//
#include <hip/hip_runtime.h>
#include <math.h>

namespace {
constexpr int kB = 16;
constexpr int kV = 500000;
constexpr int kF = 1000000;
constexpr float kEps = 1e-6f;
constexpr int kNB = (kV + 255) / 256;   // 1954

constexpr size_t kVtxTFloats = (size_t)kV * 48;   // [V][16][3]
constexpr size_t kFnFloats   = (size_t)kF * 48;   // [F][16][3]
constexpr size_t kIntBytes   = ((size_t)kV + (kV + 1) + kNB + 3 * (size_t)kF) * 4;
constexpr size_t kWsB = kVtxTFloats * 4 + kFnFloats * 4 + kIntBytes;  // ~304 MB
constexpr size_t kWsA = kVtxTFloats * 4 + kIntBytes;                  // ~112 MB
constexpr size_t kWsC = kIntBytes;                                    // ~16 MB
}

// a*b - c*d unfused: degenerate faces cancel EXACTLY (matches numpy); FMA
// contraction would leave ulp noise that normalization amplifies to O(1).
__device__ __forceinline__ float cross_comp(float a, float b, float c, float d) {
    return __fsub_rn(__fmul_rn(a, b), __fmul_rn(c, d));
}

// group-local float index i (0..23), compile-time constant after unroll.
__device__ __forceinline__ float gf(const float4 v[6], int i) {
    const float4 q = v[i >> 2];
    switch (i & 3) { case 0: return q.x; case 1: return q.y; case 2: return q.z; default: return q.w; }
}
__device__ __forceinline__ void sf(float4 v[6], int i, float x) {
    float4& q = v[i >> 2];
    switch (i & 3) { case 0: q.x = x; break; case 1: q.y = x; break; case 2: q.z = x; break; default: q.w = x; }
}
__device__ __forceinline__ void load_grp(const float* rec, int g, float4 v[6]) {
    const float4* p = reinterpret_cast<const float4*>(rec + 24 * g);
#pragma unroll
    for (int k = 0; k < 6; ++k) v[k] = p[k];
}

// ---------- CSR build (bitwise-deterministic end state) ----------

__global__ __launch_bounds__(256) void zero_count_kernel(int* __restrict__ count) {
    int i = blockIdx.x * 256 + threadIdx.x;
    if (i < kV) count[i] = 0;
}

__global__ __launch_bounds__(256) void count_kernel(
    const int* __restrict__ faces, int* __restrict__ count)
{
    int i = blockIdx.x * 256 + threadIdx.x;
    if (i >= 3 * kF) return;
    atomicAdd(&count[faces[i]], 1);
}

__device__ __forceinline__ int block_incl_scan256(int x, int* lds) {
    int lane = threadIdx.x & 63;
    int wave = threadIdx.x >> 6;
    for (int d = 1; d < 64; d <<= 1) {
        int y = __shfl_up(x, d, 64);
        if (lane >= d) x += y;
    }
    if (lane == 63) lds[wave] = x;
    __syncthreads();
    int add = 0;
    for (int w = 0; w < wave; ++w) add += lds[w];
    __syncthreads();
    return x + add;
}

__global__ __launch_bounds__(256) void scan_block_kernel(
    const int* __restrict__ count, int* __restrict__ offs,
    int* __restrict__ blockSums)
{
    __shared__ int lds[4];
    int i = blockIdx.x * 256 + threadIdx.x;
    int x = (i < kV) ? count[i] : 0;
    int incl = block_incl_scan256(x, lds);
    if (i < kV) offs[i] = incl - x;
    if (threadIdx.x == 255) blockSums[blockIdx.x] = incl;
}

__global__ __launch_bounds__(256) void scan_sums_kernel(int* __restrict__ blockSums) {
    __shared__ int lds[4];
    __shared__ int carry;
    if (threadIdx.x == 0) carry = 0;
    __syncthreads();
    for (int base = 0; base < kNB; base += 256) {
        int i = base + threadIdx.x;
        int x = (i < kNB) ? blockSums[i] : 0;
        int incl = block_incl_scan256(x, lds);
        int c = carry;
        __syncthreads();
        if (i < kNB) blockSums[i] = incl - x + c;
        if (threadIdx.x == 255) carry = c + incl;
        __syncthreads();
    }
}

__global__ __launch_bounds__(256) void add_offsets_kernel(
    int* __restrict__ offs, const int* __restrict__ blockSums)
{
    int i = blockIdx.x * 256 + threadIdx.x;
    if (i < kV) offs[i] += blockSums[i >> 8];
    if (i == kV) offs[kV] = 3 * kF;
}

__global__ __launch_bounds__(256) void fill_adj_kernel(
    const int* __restrict__ faces, const int* __restrict__ offs,
    int* __restrict__ count, int* __restrict__ adj)
{
    int i = blockIdx.x * 256 + threadIdx.x;
    if (i >= 3 * kF) return;
    int v = faces[i];
    int f = i / 3;
    int old = atomicSub(&count[v], 1);
    adj[offs[v] + old - 1] = f;
}

// canonicalize slot order -> bitwise-deterministic adj -> deterministic fp sums
__global__ __launch_bounds__(256) void sort_rows_kernel(
    const int* __restrict__ offs, int* __restrict__ adj)
{
    int v = blockIdx.x * 256 + threadIdx.x;
    if (v >= kV) return;
    int s = offs[v], e = offs[v + 1];
    for (int i = s + 1; i < e; ++i) {
        int key = adj[i];
        int j = i - 1;
        while (j >= s && adj[j] > key) { adj[j + 1] = adj[j]; --j; }
        adj[j + 1] = key;
    }
}

// ---------- transposed-layout path ----------

// verts [B][V][3] -> vtx_t [V][16][3] (192 B record per vertex, 64B-aligned)
__global__ __launch_bounds__(256) void transpose_kernel(
    const float* __restrict__ verts, float* __restrict__ vtx_t)
{
    int v = blockIdx.x * 256 + threadIdx.x;
    if (v >= kV) return;
    float* r = vtx_t + (size_t)v * 48;
#pragma unroll
    for (int b = 0; b < kB; ++b) {
        const float* p = verts + ((size_t)b * kV + v) * 3;
        r[3 * b + 0] = p[0];
        r[3 * b + 1] = p[1];
        r[3 * b + 2] = p[2];
    }
}

// Per face: gather 3 vertex records (576 B, fully used), compute 16 crosses,
// write fn record (192 B contiguous) + areas (coalesced, lane = f).
__global__ __launch_bounds__(256) void face_kernel(
    const float* __restrict__ vtx_t, const int* __restrict__ faces,
    float* __restrict__ fn, float* __restrict__ areas)
{
    int f = blockIdx.x * 256 + threadIdx.x;
    if (f >= kF) return;
    int i0 = faces[3 * f + 0];
    int i1 = faces[3 * f + 1];
    int i2 = faces[3 * f + 2];
    const float* r0 = vtx_t + (size_t)i0 * 48;
    const float* r1 = vtx_t + (size_t)i1 * 48;
    const float* r2 = vtx_t + (size_t)i2 * 48;
    float* fr = fn + (size_t)f * 48;

#pragma unroll
    for (int g = 0; g < 2; ++g) {          // batch groups of 8 (VGPR control)
        float4 a[6], b[6], c[6], o[6];
        load_grp(r0, g, a);
        load_grp(r1, g, b);
        load_grp(r2, g, c);
#pragma unroll
        for (int bb = 0; bb < 8; ++bb) {
            float x0 = gf(a, 3 * bb), y0 = gf(a, 3 * bb + 1), z0 = gf(a, 3 * bb + 2);
            float x1 = gf(b, 3 * bb), y1 = gf(b, 3 * bb + 1), z1 = gf(b, 3 * bb + 2);
            float x2 = gf(c, 3 * bb), y2 = gf(c, 3 * bb + 1), z2 = gf(c, 3 * bb + 2);
            float e1x = x1 - x0, e1y = y1 - y0, e1z = z1 - z0;
            float e2x = x2 - x1, e2y = y2 - y1, e2z = z2 - z1;
            float nx = cross_comp(e1y, e2z, e1z, e2y);
            float ny = cross_comp(e1z, e2x, e1x, e2z);
            float nz = cross_comp(e1x, e2y, e1y, e2x);
            sf(o, 3 * bb + 0, nx);
            sf(o, 3 * bb + 1, ny);
            sf(o, 3 * bb + 2, nz);
            areas[(size_t)(8 * g + bb) * kF + f] =
                0.5f * sqrtf(nx * nx + ny * ny + nz * nz);
        }
        float4* q = reinterpret_cast<float4*>(fr + 24 * g);
#pragma unroll
        for (int k = 0; k < 6; ++k) q[k] = o[k];
    }
}

// Per vertex: walk sorted CSR, gather fn records (192 B, fully used),
// accumulate 48 sums, normalize, write out [B][V][3].
__global__ __launch_bounds__(256) void vertex_kernel_fn(
    const float* __restrict__ fn, const int* __restrict__ offs,
    const int* __restrict__ adj, float* __restrict__ out)
{
    int v = blockIdx.x * 256 + threadIdx.x;
    if (v >= kV) return;
    int s = offs[v], e = offs[v + 1];

    float ax[kB], ay[kB], az[kB];
#pragma unroll
    for (int b = 0; b < kB; ++b) { ax[b] = 0.f; ay[b] = 0.f; az[b] = 0.f; }

    for (int j = s; j < e; ++j) {
        const float* fr = fn + (size_t)adj[j] * 48;
#pragma unroll
        for (int g = 0; g < 2; ++g) {
            float4 a[6];
            load_grp(fr, g, a);
#pragma unroll
            for (int bb = 0; bb < 8; ++bb) {
                int bi = 8 * g + bb;
                ax[bi] += gf(a, 3 * bb + 0);
                ay[bi] += gf(a, 3 * bb + 1);
                az[bi] += gf(a, 3 * bb + 2);
            }
        }
    }

#pragma unroll
    for (int b = 0; b < kB; ++b) {
        float n = sqrtf(ax[b] * ax[b] + ay[b] * ay[b] + az[b] * az[b]);
        float inv = 1.0f / fmaxf(n, kEps);
        size_t o = ((size_t)b * kV + v) * 3;
        out[o + 0] = ax[b] * inv;
        out[o + 1] = ay[b] * inv;
        out[o + 2] = az[b] * inv;
    }
}

// Option A: no fn buffer — recompute crosses from vtx_t gathers.
__global__ __launch_bounds__(256) void vertex_kernel_recompute(
    const float* __restrict__ vtx_t, const int* __restrict__ faces,
    const int* __restrict__ offs, const int* __restrict__ adj,
    float* __restrict__ out)
{
    int v = blockIdx.x * 256 + threadIdx.x;
    if (v >= kV) return;
    int s = offs[v], e = offs[v + 1];

    float ax[kB], ay[kB], az[kB];
#pragma unroll
    for (int b = 0; b < kB; ++b) { ax[b] = 0.f; ay[b] = 0.f; az[b] = 0.f; }

    for (int j = s; j < e; ++j) {
        int f = adj[j];
        int i0 = faces[3 * f + 0];
        int i1 = faces[3 * f + 1];
        int i2 = faces[3 * f + 2];
        const float* r0 = vtx_t + (size_t)i0 * 48;
        const float* r1 = vtx_t + (size_t)i1 * 48;
        const float* r2 = vtx_t + (size_t)i2 * 48;
#pragma unroll
        for (int g = 0; g < 2; ++g) {
            float4 a[6], b4[6], c[6];
            load_grp(r0, g, a);
            load_grp(r1, g, b4);
            load_grp(r2, g, c);
#pragma unroll
            for (int bb = 0; bb < 8; ++bb) {
                float x0 = gf(a, 3 * bb), y0 = gf(a, 3 * bb + 1), z0 = gf(a, 3 * bb + 2);
                float x1 = gf(b4, 3 * bb), y1 = gf(b4, 3 * bb + 1), z1 = gf(b4, 3 * bb + 2);
                float x2 = gf(c, 3 * bb), y2 = gf(c, 3 * bb + 1), z2 = gf(c, 3 * bb + 2);
                float e1x = x1 - x0, e1y = y1 - y0, e1z = z1 - z0;
                float e2x = x2 - x1, e2y = y2 - y1, e2z = z2 - z1;
                int bi = 8 * g + bb;
                ax[bi] += cross_comp(e1y, e2z, e1z, e2y);
                ay[bi] += cross_comp(e1z, e2x, e1x, e2z);
                az[bi] += cross_comp(e1x, e2y, e1y, e2x);
            }
        }
    }

#pragma unroll
    for (int b = 0; b < kB; ++b) {
        float n = sqrtf(ax[b] * ax[b] + ay[b] * ay[b] + az[b] * az[b]);
        float inv = 1.0f / fmaxf(n, kEps);
        size_t o = ((size_t)b * kV + v) * 3;
        out[o + 0] = ax[b] * inv;
        out[o + 1] = ay[b] * inv;
        out[o + 2] = az[b] * inv;
    }
}

// Option A area kernel (original verts layout would overfetch; use vtx_t).
__global__ __launch_bounds__(256) void area_kernel_t(
    const float* __restrict__ vtx_t, const int* __restrict__ faces,
    float* __restrict__ areas)
{
    int f = blockIdx.x * 256 + threadIdx.x;
    if (f >= kF) return;
    int i0 = faces[3 * f + 0];
    int i1 = faces[3 * f + 1];
    int i2 = faces[3 * f + 2];
    const float* r0 = vtx_t + (size_t)i0 * 48;
    const float* r1 = vtx_t + (size_t)i1 * 48;
    const float* r2 = vtx_t + (size_t)i2 * 48;
#pragma unroll
    for (int g = 0; g < 2; ++g) {
        float4 a[6], b[6], c[6];
        load_grp(r0, g, a);
        load_grp(r1, g, b);
        load_grp(r2, g, c);
#pragma unroll
        for (int bb = 0; bb < 8; ++bb) {
            float x0 = gf(a, 3 * bb), y0 = gf(a, 3 * bb + 1), z0 = gf(a, 3 * bb + 2);
            float x1 = gf(b, 3 * bb), y1 = gf(b, 3 * bb + 1), z1 = gf(b, 3 * bb + 2);
            float x2 = gf(c, 3 * bb), y2 = gf(c, 3 * bb + 1), z2 = gf(c, 3 * bb + 2);
            float e1x = x1 - x0, e1y = y1 - y0, e1z = z1 - z0;
            float e2x = x2 - x1, e2y = y2 - y1, e2z = z2 - z1;
            float nx = cross_comp(e1y, e2z, e1z, e2y);
            float ny = cross_comp(e1z, e2x, e1x, e2z);
            float nz = cross_comp(e1x, e2y, e1y, e2x);
            areas[(size_t)(8 * g + bb) * kF + f] =
                0.5f * sqrtf(nx * nx + ny * ny + nz * nz);
        }
    }
}

// ---------- R3 path kernels (ws >= 16 MB only) ----------

__global__ __launch_bounds__(256) void area_kernel_orig(
    const float* __restrict__ verts, const int* __restrict__ faces,
    float* __restrict__ areas)
{
    int f = blockIdx.x * 256 + threadIdx.x;
    if (f >= kF) return;
    int i0 = faces[3 * f + 0];
    int i1 = faces[3 * f + 1];
    int i2 = faces[3 * f + 2];
    size_t o0 = 3 * (size_t)i0, o1 = 3 * (size_t)i1, o2 = 3 * (size_t)i2;
#pragma unroll
    for (int b = 0; b < kB; ++b) {
        const float* vb = verts + (size_t)b * kV * 3;
        float x0 = vb[o0], y0 = vb[o0 + 1], z0 = vb[o0 + 2];
        float x1 = vb[o1], y1 = vb[o1 + 1], z1 = vb[o1 + 2];
        float x2 = vb[o2], y2 = vb[o2 + 1], z2 = vb[o2 + 2];
        float e1x = x1 - x0, e1y = y1 - y0, e1z = z1 - z0;
        float e2x = x2 - x1, e2y = y2 - y1, e2z = z2 - z1;
        float nx = cross_comp(e1y, e2z, e1z, e2y);
        float ny = cross_comp(e1z, e2x, e1x, e2z);
        float nz = cross_comp(e1x, e2y, e1y, e2x);
        areas[(size_t)b * kF + f] = 0.5f * sqrtf(nx * nx + ny * ny + nz * nz);
    }
}

__global__ __launch_bounds__(256) void gather_normalize_orig(
    const float* __restrict__ verts, const int* __restrict__ faces,
    const int* __restrict__ offs, const int* __restrict__ adj,
    float* __restrict__ out)
{
    int v = blockIdx.x * 256 + threadIdx.x;
    if (v >= kV) return;
    int s = offs[v], e = offs[v + 1];
    float ax[kB], ay[kB], az[kB];
#pragma unroll
    for (int b = 0; b < kB; ++b) { ax[b] = 0.f; ay[b] = 0.f; az[b] = 0.f; }
    for (int j = s; j < e; ++j) {
        int f = adj[j];
        int i0 = faces[3 * f + 0];
        int i1 = faces[3 * f + 1];
        int i2 = faces[3 * f + 2];
        size_t o0 = 3 * (size_t)i0, o1 = 3 * (size_t)i1, o2 = 3 * (size_t)i2;
#pragma unroll
        for (int b = 0; b < kB; ++b) {
            const float* vb = verts + (size_t)b * kV * 3;
            float x0 = vb[o0], y0 = vb[o0 + 1], z0 = vb[o0 + 2];
            float x1 = vb[o1], y1 = vb[o1 + 1], z1 = vb[o1 + 2];
            float x2 = vb[o2], y2 = vb[o2 + 1], z2 = vb[o2 + 2];
            float e1x = x1 - x0, e1y = y1 - y0, e1z = z1 - z0;
            float e2x = x2 - x1, e2y = y2 - y1, e2z = z2 - z1;
            ax[b] += cross_comp(e1y, e2z, e1z, e2y);
            ay[b] += cross_comp(e1z, e2x, e1x, e2z);
            az[b] += cross_comp(e1x, e2y, e1y, e2x);
        }
    }
#pragma unroll
    for (int b = 0; b < kB; ++b) {
        float n = sqrtf(ax[b] * ax[b] + ay[b] * ay[b] + az[b] * az[b]);
        float inv = 1.0f / fmaxf(n, kEps);
        size_t o = ((size_t)b * kV + v) * 3;
        out[o + 0] = ax[b] * inv;
        out[o + 1] = ay[b] * inv;
        out[o + 2] = az[b] * inv;
    }
}

// ---------- R1 fallback ----------

__global__ __launch_bounds__(256) void face_normals_atomic_kernel(
    const float* __restrict__ verts, const int* __restrict__ faces,
    float* __restrict__ vnorm, float* __restrict__ areas)
{
    long long tid = (long long)blockIdx.x * blockDim.x + threadIdx.x;
    if (tid >= (long long)kB * kF) return;
    int f = (int)(tid % kF);
    int b = (int)(tid / kF);
    int i0 = faces[3 * f + 0], i1 = faces[3 * f + 1], i2 = faces[3 * f + 2];
    const float* vb = verts + (size_t)b * kV * 3;
    size_t o0 = 3 * (size_t)i0, o1 = 3 * (size_t)i1, o2 = 3 * (size_t)i2;
    float x0 = vb[o0], y0 = vb[o0 + 1], z0 = vb[o0 + 2];
    float x1 = vb[o1], y1 = vb[o1 + 1], z1 = vb[o1 + 2];
    float x2 = vb[o2], y2 = vb[o2 + 1], z2 = vb[o2 + 2];
    float e1x = x1 - x0, e1y = y1 - y0, e1z = z1 - z0;
    float e2x = x2 - x1, e2y = y2 - y1, e2z = z2 - z1;
    float nx = cross_comp(e1y, e2z, e1z, e2y);
    float ny = cross_comp(e1z, e2x, e1x, e2z);
    float nz = cross_comp(e1x, e2y, e1y, e2x);
    float* vn = vnorm + (size_t)b * kV * 3;
    unsafeAtomicAdd(&vn[o0 + 0], nx); unsafeAtomicAdd(&vn[o0 + 1], ny); unsafeAtomicAdd(&vn[o0 + 2], nz);
    unsafeAtomicAdd(&vn[o1 + 0], nx); unsafeAtomicAdd(&vn[o1 + 1], ny); unsafeAtomicAdd(&vn[o1 + 2], nz);
    unsafeAtomicAdd(&vn[o2 + 0], nx); unsafeAtomicAdd(&vn[o2 + 1], ny); unsafeAtomicAdd(&vn[o2 + 2], nz);
    areas[(size_t)b * kF + f] = 0.5f * sqrtf(nx * nx + ny * ny + nz * nz);
}

__global__ __launch_bounds__(256) void normalize_inplace_kernel(float* __restrict__ vnorm) {
    long long tid = (long long)blockIdx.x * blockDim.x + threadIdx.x;
    if (tid >= (long long)kB * kV) return;
    size_t o = 3 * (size_t)tid;
    float x = vnorm[o], y = vnorm[o + 1], z = vnorm[o + 2];
    float n = sqrtf(x * x + y * y + z * z);
    float inv = 1.0f / fmaxf(n, kEps);
    vnorm[o] = x * inv; vnorm[o + 1] = y * inv; vnorm[o + 2] = z * inv;
}

// ---------- launch ----------

static void build_csr(const int* faces, int* count, int* offs, int* blockSums,
                      int* adj, hipStream_t stream) {
    int gInc = (3 * kF + 255) / 256;
    zero_count_kernel<<<kNB, 256, 0, stream>>>(count);
    count_kernel<<<gInc, 256, 0, stream>>>(faces, count);
    scan_block_kernel<<<kNB, 256, 0, stream>>>(count, offs, blockSums);
    scan_sums_kernel<<<1, 256, 0, stream>>>(blockSums);
    add_offsets_kernel<<<(kV + 1 + 255) / 256, 256, 0, stream>>>(offs, blockSums);
    fill_adj_kernel<<<gInc, 256, 0, stream>>>(faces, offs, count, adj);
    sort_rows_kernel<<<kNB, 256, 0, stream>>>(offs, adj);
}

extern "C" void kernel_launch(void* const* d_in, const int* in_sizes, int n_in,
                              void* d_out, int out_size, void* d_ws, size_t ws_size,
                              hipStream_t stream) {
    const float* verts = (const float*)d_in[0];
    const int*   faces = (const int*)d_in[1];

    float* out   = (float*)d_out;
    float* vecs  = out;                               // B*V*3
    float* areas = out + (size_t)kB * kV * 3;         // B*F

    int gF = (kF + 255) / 256;

    if (ws_size >= kWsB) {
        float* vtx_t = (float*)d_ws;                  // [V][16][3]
        float* fn    = vtx_t + kVtxTFloats;           // [F][16][3]
        int* count     = (int*)(fn + kFnFloats);
        int* offs      = count + kV;
        int* blockSums = offs + (kV + 1);
        int* adj       = blockSums + kNB;

        build_csr(faces, count, offs, blockSums, adj, stream);
        transpose_kernel<<<kNB, 256, 0, stream>>>(verts, vtx_t);
        face_kernel<<<gF, 256, 0, stream>>>(vtx_t, faces, fn, areas);
        vertex_kernel_fn<<<kNB, 256, 0, stream>>>(fn, offs, adj, vecs);
    } else if (ws_size >= kWsA) {
        float* vtx_t = (float*)d_ws;
        int* count     = (int*)(vtx_t + kVtxTFloats);
        int* offs      = count + kV;
        int* blockSums = offs + (kV + 1);
        int* adj       = blockSums + kNB;

        build_csr(faces, count, offs, blockSums, adj, stream);
        transpose_kernel<<<kNB, 256, 0, stream>>>(verts, vtx_t);
        area_kernel_t<<<gF, 256, 0, stream>>>(vtx_t, faces, areas);
        vertex_kernel_recompute<<<kNB, 256, 0, stream>>>(vtx_t, faces, offs, adj, vecs);
    } else if (ws_size >= kWsC) {
        int* count     = (int*)d_ws;
        int* offs      = count + kV;
        int* blockSums = offs + (kV + 1);
        int* adj       = blockSums + kNB;

        build_csr(faces, count, offs, blockSums, adj, stream);
        area_kernel_orig<<<gF, 256, 0, stream>>>(verts, faces, areas);
        gather_normalize_orig<<<kNB, 256, 0, stream>>>(verts, faces, offs, adj, vecs);
    } else {
        hipMemsetAsync(vecs, 0, (size_t)kB * kV * 3 * sizeof(float), stream);
        long long nf = (long long)kB * kF;
        face_normals_atomic_kernel<<<(int)((nf + 255) / 256), 256, 0, stream>>>(verts, faces, vecs, areas);
        long long nv = (long long)kB * kV;
        normalize_inplace_kernel<<<(int)((nv + 255) / 256), 256, 0, stream>>>(vecs);
    }
}

// Round 5
// 1008.542 us; speedup vs baseline: 6.9722x; 1.0466x over previous
//
#include <hip/hip_runtime.h>
#include <math.h>

namespace {
constexpr int kB = 16;
constexpr int kHalfB = 8;                 // batches per half
constexpr int kV = 500000;
constexpr int kF = 1000000;
constexpr float kEps = 1e-6f;
constexpr int kNB = (kV + 255) / 256;     // 1954

constexpr int kRec = 32;                  // floats per padded record (128 B line)
constexpr size_t kVtx8Floats = (size_t)kV * kRec;   // 64 MB
constexpr size_t kFn8Floats  = (size_t)kF * kRec;   // 128 MB
constexpr size_t kIntBytes   = ((size_t)kV + (kV + 1) + kNB + 3 * (size_t)kF) * 4;
constexpr size_t kWsHalf = (kVtx8Floats + kFn8Floats) * 4 + kIntBytes;  // ~208 MB
constexpr size_t kWsC    = kIntBytes;                                   // ~16 MB
}

// a*b - c*d unfused: degenerate faces cancel EXACTLY (matches numpy); FMA
// contraction would leave ulp noise that normalization amplifies to O(1).
__device__ __forceinline__ float cross_comp(float a, float b, float c, float d) {
    return __fsub_rn(__fmul_rn(a, b), __fmul_rn(c, d));
}

// element i (0..23) of a 6-float4 register block; i compile-time after unroll
__device__ __forceinline__ float gf(const float4 v[6], int i) {
    const float4 q = v[i >> 2];
    switch (i & 3) { case 0: return q.x; case 1: return q.y; case 2: return q.z; default: return q.w; }
}
__device__ __forceinline__ void sf(float4 v[6], int i, float x) {
    float4& q = v[i >> 2];
    switch (i & 3) { case 0: q.x = x; break; case 1: q.y = x; break; case 2: q.z = x; break; default: q.w = x; }
}
// load the 96 used bytes of a 128B-aligned record (one L2/L3 line)
__device__ __forceinline__ void load_rec(const float* rec, float4 v[6]) {
    const float4* p = reinterpret_cast<const float4*>(rec);
#pragma unroll
    for (int k = 0; k < 6; ++k) v[k] = p[k];
}

// ---------- CSR build (bitwise-deterministic end state) ----------

__global__ __launch_bounds__(256) void zero_count_kernel(int* __restrict__ count) {
    int i = blockIdx.x * 256 + threadIdx.x;
    if (i < kV) count[i] = 0;
}

__global__ __launch_bounds__(256) void count_kernel(
    const int* __restrict__ faces, int* __restrict__ count)
{
    int i = blockIdx.x * 256 + threadIdx.x;
    if (i >= 3 * kF) return;
    atomicAdd(&count[faces[i]], 1);
}

__device__ __forceinline__ int block_incl_scan256(int x, int* lds) {
    int lane = threadIdx.x & 63;
    int wave = threadIdx.x >> 6;
    for (int d = 1; d < 64; d <<= 1) {
        int y = __shfl_up(x, d, 64);
        if (lane >= d) x += y;
    }
    if (lane == 63) lds[wave] = x;
    __syncthreads();
    int add = 0;
    for (int w = 0; w < wave; ++w) add += lds[w];
    __syncthreads();
    return x + add;
}

__global__ __launch_bounds__(256) void scan_block_kernel(
    const int* __restrict__ count, int* __restrict__ offs,
    int* __restrict__ blockSums)
{
    __shared__ int lds[4];
    int i = blockIdx.x * 256 + threadIdx.x;
    int x = (i < kV) ? count[i] : 0;
    int incl = block_incl_scan256(x, lds);
    if (i < kV) offs[i] = incl - x;
    if (threadIdx.x == 255) blockSums[blockIdx.x] = incl;
}

__global__ __launch_bounds__(256) void scan_sums_kernel(int* __restrict__ blockSums) {
    __shared__ int lds[4];
    __shared__ int carry;
    if (threadIdx.x == 0) carry = 0;
    __syncthreads();
    for (int base = 0; base < kNB; base += 256) {
        int i = base + threadIdx.x;
        int x = (i < kNB) ? blockSums[i] : 0;
        int incl = block_incl_scan256(x, lds);
        int c = carry;
        __syncthreads();
        if (i < kNB) blockSums[i] = incl - x + c;
        if (threadIdx.x == 255) carry = c + incl;
        __syncthreads();
    }
}

__global__ __launch_bounds__(256) void add_offsets_kernel(
    int* __restrict__ offs, const int* __restrict__ blockSums)
{
    int i = blockIdx.x * 256 + threadIdx.x;
    if (i < kV) offs[i] += blockSums[i >> 8];
    if (i == kV) offs[kV] = 3 * kF;
}

__global__ __launch_bounds__(256) void fill_adj_kernel(
    const int* __restrict__ faces, const int* __restrict__ offs,
    int* __restrict__ count, int* __restrict__ adj)
{
    int i = blockIdx.x * 256 + threadIdx.x;
    if (i >= 3 * kF) return;
    int v = faces[i];
    int f = i / 3;
    int old = atomicSub(&count[v], 1);
    adj[offs[v] + old - 1] = f;
}

// canonicalize slot order -> bitwise-deterministic adj -> deterministic fp sums
__global__ __launch_bounds__(256) void sort_rows_kernel(
    const int* __restrict__ offs, int* __restrict__ adj)
{
    int v = blockIdx.x * 256 + threadIdx.x;
    if (v >= kV) return;
    int s = offs[v], e = offs[v + 1];
    for (int i = s + 1; i < e; ++i) {
        int key = adj[i];
        int j = i - 1;
        while (j >= s && adj[j] > key) { adj[j + 1] = adj[j]; --j; }
        adj[j + 1] = key;
    }
}

// ---------- half-batch padded-record path ----------

// verts [B][V][3] -> vtx8 [V][32f] (batches half*8..half*8+7 in floats 0..23)
__global__ __launch_bounds__(256) void transpose_half_kernel(
    const float* __restrict__ verts, float* __restrict__ vtx8, int half)
{
    int v = blockIdx.x * 256 + threadIdx.x;
    if (v >= kV) return;
    float4 r[6];
#pragma unroll
    for (int bb = 0; bb < kHalfB; ++bb) {
        const float* p = verts + ((size_t)(half * kHalfB + bb) * kV + v) * 3;
        sf(r, 3 * bb + 0, p[0]);
        sf(r, 3 * bb + 1, p[1]);
        sf(r, 3 * bb + 2, p[2]);
    }
    float4* q = reinterpret_cast<float4*>(vtx8 + (size_t)v * kRec);
#pragma unroll
    for (int k = 0; k < 6; ++k) q[k] = r[k];
}

// Per face: 3 one-line record gathers, 8 crosses, fn record write + areas.
__global__ __launch_bounds__(256) void face_half_kernel(
    const float* __restrict__ vtx8, const int* __restrict__ faces,
    float* __restrict__ fn8, float* __restrict__ areas, int half)
{
    int f = blockIdx.x * 256 + threadIdx.x;
    if (f >= kF) return;
    int i0 = faces[3 * f + 0];
    int i1 = faces[3 * f + 1];
    int i2 = faces[3 * f + 2];
    float4 a[6], b[6], c[6], o[6];
    load_rec(vtx8 + (size_t)i0 * kRec, a);
    load_rec(vtx8 + (size_t)i1 * kRec, b);
    load_rec(vtx8 + (size_t)i2 * kRec, c);
#pragma unroll
    for (int bb = 0; bb < kHalfB; ++bb) {
        float x0 = gf(a, 3 * bb), y0 = gf(a, 3 * bb + 1), z0 = gf(a, 3 * bb + 2);
        float x1 = gf(b, 3 * bb), y1 = gf(b, 3 * bb + 1), z1 = gf(b, 3 * bb + 2);
        float x2 = gf(c, 3 * bb), y2 = gf(c, 3 * bb + 1), z2 = gf(c, 3 * bb + 2);
        float e1x = x1 - x0, e1y = y1 - y0, e1z = z1 - z0;
        float e2x = x2 - x1, e2y = y2 - y1, e2z = z2 - z1;
        float nx = cross_comp(e1y, e2z, e1z, e2y);
        float ny = cross_comp(e1z, e2x, e1x, e2z);
        float nz = cross_comp(e1x, e2y, e1y, e2x);
        sf(o, 3 * bb + 0, nx);
        sf(o, 3 * bb + 1, ny);
        sf(o, 3 * bb + 2, nz);
        // areas: never re-read -> non-temporal, keep L3 for the tables
        __builtin_nontemporal_store(
            0.5f * sqrtf(nx * nx + ny * ny + nz * nz),
            &areas[(size_t)(half * kHalfB + bb) * kF + f]);
    }
    float4* q = reinterpret_cast<float4*>(fn8 + (size_t)f * kRec);
#pragma unroll
    for (int k = 0; k < 6; ++k) q[k] = o[k];   // fn IS re-read: normal store
}

// Per vertex: walk sorted CSR, one-line fn gathers, 24 sums, normalize.
__global__ __launch_bounds__(256) void vertex_half_kernel(
    const float* __restrict__ fn8, const int* __restrict__ offs,
    const int* __restrict__ adj, float* __restrict__ out, int half)
{
    int v = blockIdx.x * 256 + threadIdx.x;
    if (v >= kV) return;
    int s = offs[v], e = offs[v + 1];

    float ax[kHalfB], ay[kHalfB], az[kHalfB];
#pragma unroll
    for (int bb = 0; bb < kHalfB; ++bb) { ax[bb] = 0.f; ay[bb] = 0.f; az[bb] = 0.f; }

    for (int j = s; j < e; ++j) {
        float4 a[6];
        load_rec(fn8 + (size_t)adj[j] * kRec, a);
#pragma unroll
        for (int bb = 0; bb < kHalfB; ++bb) {
            ax[bb] += gf(a, 3 * bb + 0);
            ay[bb] += gf(a, 3 * bb + 1);
            az[bb] += gf(a, 3 * bb + 2);
        }
    }

#pragma unroll
    for (int bb = 0; bb < kHalfB; ++bb) {
        float n = sqrtf(ax[bb] * ax[bb] + ay[bb] * ay[bb] + az[bb] * az[bb]);
        float inv = 1.0f / fmaxf(n, kEps);
        size_t o = ((size_t)(half * kHalfB + bb) * kV + v) * 3;
        __builtin_nontemporal_store(ax[bb] * inv, &out[o + 0]);
        __builtin_nontemporal_store(ay[bb] * inv, &out[o + 1]);
        __builtin_nontemporal_store(az[bb] * inv, &out[o + 2]);
    }
}

// ---------- R3 path (ws >= 16 MB only) ----------

__global__ __launch_bounds__(256) void area_kernel_orig(
    const float* __restrict__ verts, const int* __restrict__ faces,
    float* __restrict__ areas)
{
    int f = blockIdx.x * 256 + threadIdx.x;
    if (f >= kF) return;
    int i0 = faces[3 * f + 0];
    int i1 = faces[3 * f + 1];
    int i2 = faces[3 * f + 2];
    size_t o0 = 3 * (size_t)i0, o1 = 3 * (size_t)i1, o2 = 3 * (size_t)i2;
#pragma unroll
    for (int b = 0; b < kB; ++b) {
        const float* vb = verts + (size_t)b * kV * 3;
        float x0 = vb[o0], y0 = vb[o0 + 1], z0 = vb[o0 + 2];
        float x1 = vb[o1], y1 = vb[o1 + 1], z1 = vb[o1 + 2];
        float x2 = vb[o2], y2 = vb[o2 + 1], z2 = vb[o2 + 2];
        float e1x = x1 - x0, e1y = y1 - y0, e1z = z1 - z0;
        float e2x = x2 - x1, e2y = y2 - y1, e2z = z2 - z1;
        float nx = cross_comp(e1y, e2z, e1z, e2y);
        float ny = cross_comp(e1z, e2x, e1x, e2z);
        float nz = cross_comp(e1x, e2y, e1y, e2x);
        areas[(size_t)b * kF + f] = 0.5f * sqrtf(nx * nx + ny * ny + nz * nz);
    }
}

__global__ __launch_bounds__(256) void gather_normalize_orig(
    const float* __restrict__ verts, const int* __restrict__ faces,
    const int* __restrict__ offs, const int* __restrict__ adj,
    float* __restrict__ out)
{
    int v = blockIdx.x * 256 + threadIdx.x;
    if (v >= kV) return;
    int s = offs[v], e = offs[v + 1];
    float ax[kB], ay[kB], az[kB];
#pragma unroll
    for (int b = 0; b < kB; ++b) { ax[b] = 0.f; ay[b] = 0.f; az[b] = 0.f; }
    for (int j = s; j < e; ++j) {
        int f = adj[j];
        int i0 = faces[3 * f + 0];
        int i1 = faces[3 * f + 1];
        int i2 = faces[3 * f + 2];
        size_t o0 = 3 * (size_t)i0, o1 = 3 * (size_t)i1, o2 = 3 * (size_t)i2;
#pragma unroll
        for (int b = 0; b < kB; ++b) {
            const float* vb = verts + (size_t)b * kV * 3;
            float x0 = vb[o0], y0 = vb[o0 + 1], z0 = vb[o0 + 2];
            float x1 = vb[o1], y1 = vb[o1 + 1], z1 = vb[o1 + 2];
            float x2 = vb[o2], y2 = vb[o2 + 1], z2 = vb[o2 + 2];
            float e1x = x1 - x0, e1y = y1 - y0, e1z = z1 - z0;
            float e2x = x2 - x1, e2y = y2 - y1, e2z = z2 - z1;
            ax[b] += cross_comp(e1y, e2z, e1z, e2y);
            ay[b] += cross_comp(e1z, e2x, e1x, e2z);
            az[b] += cross_comp(e1x, e2y, e1y, e2x);
        }
    }
#pragma unroll
    for (int b = 0; b < kB; ++b) {
        float n = sqrtf(ax[b] * ax[b] + ay[b] * ay[b] + az[b] * az[b]);
        float inv = 1.0f / fmaxf(n, kEps);
        size_t o = ((size_t)b * kV + v) * 3;
        out[o + 0] = ax[b] * inv;
        out[o + 1] = ay[b] * inv;
        out[o + 2] = az[b] * inv;
    }
}

// ---------- R1 fallback ----------

__global__ __launch_bounds__(256) void face_normals_atomic_kernel(
    const float* __restrict__ verts, const int* __restrict__ faces,
    float* __restrict__ vnorm, float* __restrict__ areas)
{
    long long tid = (long long)blockIdx.x * blockDim.x + threadIdx.x;
    if (tid >= (long long)kB * kF) return;
    int f = (int)(tid % kF);
    int b = (int)(tid / kF);
    int i0 = faces[3 * f + 0], i1 = faces[3 * f + 1], i2 = faces[3 * f + 2];
    const float* vb = verts + (size_t)b * kV * 3;
    size_t o0 = 3 * (size_t)i0, o1 = 3 * (size_t)i1, o2 = 3 * (size_t)i2;
    float x0 = vb[o0], y0 = vb[o0 + 1], z0 = vb[o0 + 2];
    float x1 = vb[o1], y1 = vb[o1 + 1], z1 = vb[o1 + 2];
    float x2 = vb[o2], y2 = vb[o2 + 1], z2 = vb[o2 + 2];
    float e1x = x1 - x0, e1y = y1 - y0, e1z = z1 - z0;
    float e2x = x2 - x1, e2y = y2 - y1, e2z = z2 - z1;
    float nx = cross_comp(e1y, e2z, e1z, e2y);
    float ny = cross_comp(e1z, e2x, e1x, e2z);
    float nz = cross_comp(e1x, e2y, e1y, e2x);
    float* vn = vnorm + (size_t)b * kV * 3;
    unsafeAtomicAdd(&vn[o0 + 0], nx); unsafeAtomicAdd(&vn[o0 + 1], ny); unsafeAtomicAdd(&vn[o0 + 2], nz);
    unsafeAtomicAdd(&vn[o1 + 0], nx); unsafeAtomicAdd(&vn[o1 + 1], ny); unsafeAtomicAdd(&vn[o1 + 2], nz);
    unsafeAtomicAdd(&vn[o2 + 0], nx); unsafeAtomicAdd(&vn[o2 + 1], ny); unsafeAtomicAdd(&vn[o2 + 2], nz);
    areas[(size_t)b * kF + f] = 0.5f * sqrtf(nx * nx + ny * ny + nz * nz);
}

__global__ __launch_bounds__(256) void normalize_inplace_kernel(float* __restrict__ vnorm) {
    long long tid = (long long)blockIdx.x * blockDim.x + threadIdx.x;
    if (tid >= (long long)kB * kV) return;
    size_t o = 3 * (size_t)tid;
    float x = vnorm[o], y = vnorm[o + 1], z = vnorm[o + 2];
    float n = sqrtf(x * x + y * y + z * z);
    float inv = 1.0f / fmaxf(n, kEps);
    vnorm[o] = x * inv; vnorm[o + 1] = y * inv; vnorm[o + 2] = z * inv;
}

// ---------- launch ----------

static void build_csr(const int* faces, int* count, int* offs, int* blockSums,
                      int* adj, hipStream_t stream) {
    int gInc = (3 * kF + 255) / 256;
    zero_count_kernel<<<kNB, 256, 0, stream>>>(count);
    count_kernel<<<gInc, 256, 0, stream>>>(faces, count);
    scan_block_kernel<<<kNB, 256, 0, stream>>>(count, offs, blockSums);
    scan_sums_kernel<<<1, 256, 0, stream>>>(blockSums);
    add_offsets_kernel<<<(kV + 1 + 255) / 256, 256, 0, stream>>>(offs, blockSums);
    fill_adj_kernel<<<gInc, 256, 0, stream>>>(faces, offs, count, adj);
    sort_rows_kernel<<<kNB, 256, 0, stream>>>(offs, adj);
}

extern "C" void kernel_launch(void* const* d_in, const int* in_sizes, int n_in,
                              void* d_out, int out_size, void* d_ws, size_t ws_size,
                              hipStream_t stream) {
    const float* verts = (const float*)d_in[0];
    const int*   faces = (const int*)d_in[1];

    float* out   = (float*)d_out;
    float* vecs  = out;                               // B*V*3
    float* areas = out + (size_t)kB * kV * 3;         // B*F

    int gF = (kF + 255) / 256;

    if (ws_size >= kWsHalf) {
        float* vtx8 = (float*)d_ws;                   // [V][32f], 64 MB
        float* fn8  = vtx8 + kVtx8Floats;             // [F][32f], 128 MB
        int* count     = (int*)(fn8 + kFn8Floats);
        int* offs      = count + kV;
        int* blockSums = offs + (kV + 1);
        int* adj       = blockSums + kNB;

        build_csr(faces, count, offs, blockSums, adj, stream);
        for (int half = 0; half < 2; ++half) {
            transpose_half_kernel<<<kNB, 256, 0, stream>>>(verts, vtx8, half);
            face_half_kernel<<<gF, 256, 0, stream>>>(vtx8, faces, fn8, areas, half);
            vertex_half_kernel<<<kNB, 256, 0, stream>>>(fn8, offs, adj, vecs, half);
        }
    } else if (ws_size >= kWsC) {
        int* count     = (int*)d_ws;
        int* offs      = count + kV;
        int* blockSums = offs + (kV + 1);
        int* adj       = blockSums + kNB;

        build_csr(faces, count, offs, blockSums, adj, stream);
        area_kernel_orig<<<gF, 256, 0, stream>>>(verts, faces, areas);
        gather_normalize_orig<<<kNB, 256, 0, stream>>>(verts, faces, offs, adj, vecs);
    } else {
        hipMemsetAsync(vecs, 0, (size_t)kB * kV * 3 * sizeof(float), stream);
        long long nf = (long long)kB * kF;
        face_normals_atomic_kernel<<<(int)((nf + 255) / 256), 256, 0, stream>>>(verts, faces, vecs, areas);
        long long nv = (long long)kB * kV;
        normalize_inplace_kernel<<<(int)((nv + 255) / 256), 256, 0, stream>>>(vecs);
    }
}

// Round 6
// 807.791 us; speedup vs baseline: 8.7050x; 1.2485x over previous
//
#include <hip/hip_runtime.h>
#include <hip/hip_fp16.h>
#include <math.h>

namespace {
constexpr int kB = 16;
constexpr int kV = 500000;
constexpr int kF = 1000000;
constexpr float kEps = 1e-6f;
constexpr int kNB = (kV + 255) / 256;     // 1954

// vtx32: [V] records of 64 floats (48 used = 16 batches x 3 fp32, pad to 256 B)
// fn16 : [F] records of 32 uints  (24 used = 48 fp16 comps,      pad to 128 B)
constexpr size_t kVtx32Floats = (size_t)kV * 64;   // 128 MB
constexpr size_t kFn16Uints   = (size_t)kF * 32;   // 128 MB
constexpr size_t kIntBytes   = ((size_t)kV + (kV + 1) + kNB + 3 * (size_t)kF) * 4;
constexpr size_t kWs16 = kVtx32Floats * 4 + kFn16Uints * 4 + kIntBytes;  // ~272 MB
constexpr size_t kWsC  = kIntBytes;                                      // ~16 MB
}

// a*b - c*d unfused: degenerate faces cancel EXACTLY (matches numpy); FMA
// contraction would leave ulp noise that normalization amplifies to O(1).
__device__ __forceinline__ float cross_comp(float a, float b, float c, float d) {
    return __fsub_rn(__fmul_rn(a, b), __fmul_rn(c, d));
}

// element i (0..23) of a 6-float4 register block; i compile-time after unroll
__device__ __forceinline__ float gf(const float4 v[6], int i) {
    const float4 q = v[i >> 2];
    switch (i & 3) { case 0: return q.x; case 1: return q.y; case 2: return q.z; default: return q.w; }
}

__device__ __forceinline__ unsigned pack2(float a, float b) {
    __half2 h = __halves2half2(__float2half_rn(a), __float2half_rn(b));
    return __builtin_bit_cast(unsigned, h);
}
__device__ __forceinline__ float2 unpack2(unsigned u) {
    return __half22float2(__builtin_bit_cast(__half2, u));
}

// ---------- CSR build (bitwise-deterministic end state) ----------

__global__ __launch_bounds__(256) void zero_count_kernel(int* __restrict__ count) {
    int i = blockIdx.x * 256 + threadIdx.x;
    if (i < kV) count[i] = 0;
}

__global__ __launch_bounds__(256) void count_kernel(
    const int* __restrict__ faces, int* __restrict__ count)
{
    int i = blockIdx.x * 256 + threadIdx.x;
    if (i >= 3 * kF) return;
    atomicAdd(&count[faces[i]], 1);
}

__device__ __forceinline__ int block_incl_scan256(int x, int* lds) {
    int lane = threadIdx.x & 63;
    int wave = threadIdx.x >> 6;
    for (int d = 1; d < 64; d <<= 1) {
        int y = __shfl_up(x, d, 64);
        if (lane >= d) x += y;
    }
    if (lane == 63) lds[wave] = x;
    __syncthreads();
    int add = 0;
    for (int w = 0; w < wave; ++w) add += lds[w];
    __syncthreads();
    return x + add;
}

__global__ __launch_bounds__(256) void scan_block_kernel(
    const int* __restrict__ count, int* __restrict__ offs,
    int* __restrict__ blockSums)
{
    __shared__ int lds[4];
    int i = blockIdx.x * 256 + threadIdx.x;
    int x = (i < kV) ? count[i] : 0;
    int incl = block_incl_scan256(x, lds);
    if (i < kV) offs[i] = incl - x;
    if (threadIdx.x == 255) blockSums[blockIdx.x] = incl;
}

__global__ __launch_bounds__(256) void scan_sums_kernel(int* __restrict__ blockSums) {
    __shared__ int lds[4];
    __shared__ int carry;
    if (threadIdx.x == 0) carry = 0;
    __syncthreads();
    for (int base = 0; base < kNB; base += 256) {
        int i = base + threadIdx.x;
        int x = (i < kNB) ? blockSums[i] : 0;
        int incl = block_incl_scan256(x, lds);
        int c = carry;
        __syncthreads();
        if (i < kNB) blockSums[i] = incl - x + c;
        if (threadIdx.x == 255) carry = c + incl;
        __syncthreads();
    }
}

__global__ __launch_bounds__(256) void add_offsets_kernel(
    int* __restrict__ offs, const int* __restrict__ blockSums)
{
    int i = blockIdx.x * 256 + threadIdx.x;
    if (i < kV) offs[i] += blockSums[i >> 8];
    if (i == kV) offs[kV] = 3 * kF;
}

__global__ __launch_bounds__(256) void fill_adj_kernel(
    const int* __restrict__ faces, const int* __restrict__ offs,
    int* __restrict__ count, int* __restrict__ adj)
{
    int i = blockIdx.x * 256 + threadIdx.x;
    if (i >= 3 * kF) return;
    int v = faces[i];
    int f = i / 3;
    int old = atomicSub(&count[v], 1);
    adj[offs[v] + old - 1] = f;
}

// canonicalize slot order -> bitwise-deterministic adj -> deterministic fp sums
__global__ __launch_bounds__(256) void sort_rows_kernel(
    const int* __restrict__ offs, int* __restrict__ adj)
{
    int v = blockIdx.x * 256 + threadIdx.x;
    if (v >= kV) return;
    int s = offs[v], e = offs[v + 1];
    for (int i = s + 1; i < e; ++i) {
        int key = adj[i];
        int j = i - 1;
        while (j >= s && adj[j] > key) { adj[j + 1] = adj[j]; --j; }
        adj[j + 1] = key;
    }
}

// ---------- 16-batch padded-record path ----------

// verts [B][V][3] -> vtx32 [V][64f]; full 256 B written (pad zeroed, no RFO)
__global__ __launch_bounds__(256) void transpose_kernel32(
    const float* __restrict__ verts, float* __restrict__ vtx32)
{
    int v = blockIdx.x * 256 + threadIdx.x;
    if (v >= kV) return;
    float o[48];
#pragma unroll
    for (int b = 0; b < kB; ++b) {
        const float* p = verts + ((size_t)b * kV + v) * 3;
        o[3 * b + 0] = p[0];
        o[3 * b + 1] = p[1];
        o[3 * b + 2] = p[2];
    }
    float4* q = reinterpret_cast<float4*>(vtx32 + (size_t)v * 64);
#pragma unroll
    for (int k = 0; k < 12; ++k)
        q[k] = make_float4(o[4 * k], o[4 * k + 1], o[4 * k + 2], o[4 * k + 3]);
#pragma unroll
    for (int k = 12; k < 16; ++k) q[k] = make_float4(0.f, 0.f, 0.f, 0.f);
}

// Per face: 3 record gathers (2 granules each), 16 fp32 crosses, areas (fp32,
// NT), fn16 record = 48 fp16 comps written as a FULL 128 B line (no RFO).
__global__ __launch_bounds__(256) void face_kernel16(
    const float* __restrict__ vtx32, const int* __restrict__ faces,
    unsigned* __restrict__ fn16, float* __restrict__ areas)
{
    int f = blockIdx.x * 256 + threadIdx.x;
    if (f >= kF) return;
    int i0 = faces[3 * f + 0];
    int i1 = faces[3 * f + 1];
    int i2 = faces[3 * f + 2];
    const float4* r0 = reinterpret_cast<const float4*>(vtx32 + (size_t)i0 * 64);
    const float4* r1 = reinterpret_cast<const float4*>(vtx32 + (size_t)i1 * 64);
    const float4* r2 = reinterpret_cast<const float4*>(vtx32 + (size_t)i2 * 64);

    float o[48];
#pragma unroll
    for (int g = 0; g < 2; ++g) {          // 8 batches per group (VGPR control)
        float4 a[6], b[6], c[6];
#pragma unroll
        for (int k = 0; k < 6; ++k) {
            a[k] = r0[6 * g + k];
            b[k] = r1[6 * g + k];
            c[k] = r2[6 * g + k];
        }
#pragma unroll
        for (int bb = 0; bb < 8; ++bb) {
            float x0 = gf(a, 3 * bb), y0 = gf(a, 3 * bb + 1), z0 = gf(a, 3 * bb + 2);
            float x1 = gf(b, 3 * bb), y1 = gf(b, 3 * bb + 1), z1 = gf(b, 3 * bb + 2);
            float x2 = gf(c, 3 * bb), y2 = gf(c, 3 * bb + 1), z2 = gf(c, 3 * bb + 2);
            float e1x = x1 - x0, e1y = y1 - y0, e1z = z1 - z0;
            float e2x = x2 - x1, e2y = y2 - y1, e2z = z2 - z1;
            float nx = cross_comp(e1y, e2z, e1z, e2y);
            float ny = cross_comp(e1z, e2x, e1x, e2z);
            float nz = cross_comp(e1x, e2y, e1y, e2x);
            int bi = 8 * g + bb;
            o[3 * bi + 0] = nx;
            o[3 * bi + 1] = ny;
            o[3 * bi + 2] = nz;
            // areas from fp32 coords (exact as before); never re-read -> NT
            __builtin_nontemporal_store(
                0.5f * sqrtf(nx * nx + ny * ny + nz * nz),
                &areas[(size_t)bi * kF + f]);
        }
    }
    uint4* q = reinterpret_cast<uint4*>(fn16 + (size_t)f * 32);
#pragma unroll
    for (int k = 0; k < 6; ++k)
        q[k] = make_uint4(pack2(o[8 * k + 0], o[8 * k + 1]),
                          pack2(o[8 * k + 2], o[8 * k + 3]),
                          pack2(o[8 * k + 4], o[8 * k + 5]),
                          pack2(o[8 * k + 6], o[8 * k + 7]));
    q[6] = make_uint4(0u, 0u, 0u, 0u);     // full-line write: no RFO
    q[7] = make_uint4(0u, 0u, 0u, 0u);
}

// Per vertex: walk sorted CSR, ONE-granule fn16 gathers (all 16 batches),
// fp32 accumulate, normalize, NT store.
__global__ __launch_bounds__(256) void vertex_kernel16(
    const unsigned* __restrict__ fn16, const int* __restrict__ offs,
    const int* __restrict__ adj, float* __restrict__ out)
{
    int v = blockIdx.x * 256 + threadIdx.x;
    if (v >= kV) return;
    int s = offs[v], e = offs[v + 1];

    float acc[48];
#pragma unroll
    for (int i = 0; i < 48; ++i) acc[i] = 0.f;

    for (int j = s; j < e; ++j) {
        const uint4* q = reinterpret_cast<const uint4*>(fn16 + (size_t)adj[j] * 32);
        uint4 w[6];
#pragma unroll
        for (int k = 0; k < 6; ++k) w[k] = q[k];
#pragma unroll
        for (int k = 0; k < 6; ++k) {
            float2 t0 = unpack2(w[k].x), t1 = unpack2(w[k].y);
            float2 t2 = unpack2(w[k].z), t3 = unpack2(w[k].w);
            acc[8 * k + 0] += t0.x; acc[8 * k + 1] += t0.y;
            acc[8 * k + 2] += t1.x; acc[8 * k + 3] += t1.y;
            acc[8 * k + 4] += t2.x; acc[8 * k + 5] += t2.y;
            acc[8 * k + 6] += t3.x; acc[8 * k + 7] += t3.y;
        }
    }

#pragma unroll
    for (int bi = 0; bi < kB; ++bi) {
        float x = acc[3 * bi], y = acc[3 * bi + 1], z = acc[3 * bi + 2];
        float n = sqrtf(x * x + y * y + z * z);
        float inv = 1.0f / fmaxf(n, kEps);
        size_t o = ((size_t)bi * kV + v) * 3;
        __builtin_nontemporal_store(x * inv, &out[o + 0]);
        __builtin_nontemporal_store(y * inv, &out[o + 1]);
        __builtin_nontemporal_store(z * inv, &out[o + 2]);
    }
}

// ---------- R3 fallback (ws >= 16 MB) ----------

__global__ __launch_bounds__(256) void area_kernel_orig(
    const float* __restrict__ verts, const int* __restrict__ faces,
    float* __restrict__ areas)
{
    int f = blockIdx.x * 256 + threadIdx.x;
    if (f >= kF) return;
    int i0 = faces[3 * f + 0];
    int i1 = faces[3 * f + 1];
    int i2 = faces[3 * f + 2];
    size_t o0 = 3 * (size_t)i0, o1 = 3 * (size_t)i1, o2 = 3 * (size_t)i2;
#pragma unroll
    for (int b = 0; b < kB; ++b) {
        const float* vb = verts + (size_t)b * kV * 3;
        float x0 = vb[o0], y0 = vb[o0 + 1], z0 = vb[o0 + 2];
        float x1 = vb[o1], y1 = vb[o1 + 1], z1 = vb[o1 + 2];
        float x2 = vb[o2], y2 = vb[o2 + 1], z2 = vb[o2 + 2];
        float e1x = x1 - x0, e1y = y1 - y0, e1z = z1 - z0;
        float e2x = x2 - x1, e2y = y2 - y1, e2z = z2 - z1;
        float nx = cross_comp(e1y, e2z, e1z, e2y);
        float ny = cross_comp(e1z, e2x, e1x, e2z);
        float nz = cross_comp(e1x, e2y, e1y, e2x);
        areas[(size_t)b * kF + f] = 0.5f * sqrtf(nx * nx + ny * ny + nz * nz);
    }
}

__global__ __launch_bounds__(256) void gather_normalize_orig(
    const float* __restrict__ verts, const int* __restrict__ faces,
    const int* __restrict__ offs, const int* __restrict__ adj,
    float* __restrict__ out)
{
    int v = blockIdx.x * 256 + threadIdx.x;
    if (v >= kV) return;
    int s = offs[v], e = offs[v + 1];
    float ax[kB], ay[kB], az[kB];
#pragma unroll
    for (int b = 0; b < kB; ++b) { ax[b] = 0.f; ay[b] = 0.f; az[b] = 0.f; }
    for (int j = s; j < e; ++j) {
        int f = adj[j];
        int i0 = faces[3 * f + 0];
        int i1 = faces[3 * f + 1];
        int i2 = faces[3 * f + 2];
        size_t o0 = 3 * (size_t)i0, o1 = 3 * (size_t)i1, o2 = 3 * (size_t)i2;
#pragma unroll
        for (int b = 0; b < kB; ++b) {
            const float* vb = verts + (size_t)b * kV * 3;
            float x0 = vb[o0], y0 = vb[o0 + 1], z0 = vb[o0 + 2];
            float x1 = vb[o1], y1 = vb[o1 + 1], z1 = vb[o1 + 2];
            float x2 = vb[o2], y2 = vb[o2 + 1], z2 = vb[o2 + 2];
            float e1x = x1 - x0, e1y = y1 - y0, e1z = z1 - z0;
            float e2x = x2 - x1, e2y = y2 - y1, e2z = z2 - z1;
            ax[b] += cross_comp(e1y, e2z, e1z, e2y);
            ay[b] += cross_comp(e1z, e2x, e1x, e2z);
            az[b] += cross_comp(e1x, e2y, e1y, e2x);
        }
    }
#pragma unroll
    for (int b = 0; b < kB; ++b) {
        float n = sqrtf(ax[b] * ax[b] + ay[b] * ay[b] + az[b] * az[b]);
        float inv = 1.0f / fmaxf(n, kEps);
        size_t o = ((size_t)b * kV + v) * 3;
        out[o + 0] = ax[b] * inv;
        out[o + 1] = ay[b] * inv;
        out[o + 2] = az[b] * inv;
    }
}

// ---------- R1 fallback ----------

__global__ __launch_bounds__(256) void face_normals_atomic_kernel(
    const float* __restrict__ verts, const int* __restrict__ faces,
    float* __restrict__ vnorm, float* __restrict__ areas)
{
    long long tid = (long long)blockIdx.x * blockDim.x + threadIdx.x;
    if (tid >= (long long)kB * kF) return;
    int f = (int)(tid % kF);
    int b = (int)(tid / kF);
    int i0 = faces[3 * f + 0], i1 = faces[3 * f + 1], i2 = faces[3 * f + 2];
    const float* vb = verts + (size_t)b * kV * 3;
    size_t o0 = 3 * (size_t)i0, o1 = 3 * (size_t)i1, o2 = 3 * (size_t)i2;
    float x0 = vb[o0], y0 = vb[o0 + 1], z0 = vb[o0 + 2];
    float x1 = vb[o1], y1 = vb[o1 + 1], z1 = vb[o1 + 2];
    float x2 = vb[o2], y2 = vb[o2 + 1], z2 = vb[o2 + 2];
    float e1x = x1 - x0, e1y = y1 - y0, e1z = z1 - z0;
    float e2x = x2 - x1, e2y = y2 - y1, e2z = z2 - z1;
    float nx = cross_comp(e1y, e2z, e1z, e2y);
    float ny = cross_comp(e1z, e2x, e1x, e2z);
    float nz = cross_comp(e1x, e2y, e1y, e2x);
    float* vn = vnorm + (size_t)b * kV * 3;
    unsafeAtomicAdd(&vn[o0 + 0], nx); unsafeAtomicAdd(&vn[o0 + 1], ny); unsafeAtomicAdd(&vn[o0 + 2], nz);
    unsafeAtomicAdd(&vn[o1 + 0], nx); unsafeAtomicAdd(&vn[o1 + 1], ny); unsafeAtomicAdd(&vn[o1 + 2], nz);
    unsafeAtomicAdd(&vn[o2 + 0], nx); unsafeAtomicAdd(&vn[o2 + 1], ny); unsafeAtomicAdd(&vn[o2 + 2], nz);
    areas[(size_t)b * kF + f] = 0.5f * sqrtf(nx * nx + ny * ny + nz * nz);
}

__global__ __launch_bounds__(256) void normalize_inplace_kernel(float* __restrict__ vnorm) {
    long long tid = (long long)blockIdx.x * blockDim.x + threadIdx.x;
    if (tid >= (long long)kB * kV) return;
    size_t o = 3 * (size_t)tid;
    float x = vnorm[o], y = vnorm[o + 1], z = vnorm[o + 2];
    float n = sqrtf(x * x + y * y + z * z);
    float inv = 1.0f / fmaxf(n, kEps);
    vnorm[o] = x * inv; vnorm[o + 1] = y * inv; vnorm[o + 2] = z * inv;
}

// ---------- launch ----------

static void build_csr(const int* faces, int* count, int* offs, int* blockSums,
                      int* adj, hipStream_t stream) {
    int gInc = (3 * kF + 255) / 256;
    zero_count_kernel<<<kNB, 256, 0, stream>>>(count);
    count_kernel<<<gInc, 256, 0, stream>>>(faces, count);
    scan_block_kernel<<<kNB, 256, 0, stream>>>(count, offs, blockSums);
    scan_sums_kernel<<<1, 256, 0, stream>>>(blockSums);
    add_offsets_kernel<<<(kV + 1 + 255) / 256, 256, 0, stream>>>(offs, blockSums);
    fill_adj_kernel<<<gInc, 256, 0, stream>>>(faces, offs, count, adj);
    sort_rows_kernel<<<kNB, 256, 0, stream>>>(offs, adj);
}

extern "C" void kernel_launch(void* const* d_in, const int* in_sizes, int n_in,
                              void* d_out, int out_size, void* d_ws, size_t ws_size,
                              hipStream_t stream) {
    const float* verts = (const float*)d_in[0];
    const int*   faces = (const int*)d_in[1];

    float* out   = (float*)d_out;
    float* vecs  = out;                               // B*V*3
    float* areas = out + (size_t)kB * kV * 3;         // B*F

    int gF = (kF + 255) / 256;

    if (ws_size >= kWs16) {
        float*    vtx32 = (float*)d_ws;               // 128 MB
        unsigned* fn16  = (unsigned*)(vtx32 + kVtx32Floats);  // 128 MB
        int* count     = (int*)(fn16 + kFn16Uints);
        int* offs      = count + kV;
        int* blockSums = offs + (kV + 1);
        int* adj       = blockSums + kNB;

        build_csr(faces, count, offs, blockSums, adj, stream);
        transpose_kernel32<<<kNB, 256, 0, stream>>>(verts, vtx32);
        face_kernel16<<<gF, 256, 0, stream>>>(vtx32, faces, fn16, areas);
        vertex_kernel16<<<kNB, 256, 0, stream>>>(fn16, offs, adj, vecs);
    } else if (ws_size >= kWsC) {
        int* count     = (int*)d_ws;
        int* offs      = count + kV;
        int* blockSums = offs + (kV + 1);
        int* adj       = blockSums + kNB;

        build_csr(faces, count, offs, blockSums, adj, stream);
        area_kernel_orig<<<gF, 256, 0, stream>>>(verts, faces, areas);
        gather_normalize_orig<<<kNB, 256, 0, stream>>>(verts, faces, offs, adj, vecs);
    } else {
        hipMemsetAsync(vecs, 0, (size_t)kB * kV * 3 * sizeof(float), stream);
        long long nf = (long long)kB * kF;
        face_normals_atomic_kernel<<<(int)((nf + 255) / 256), 256, 0, stream>>>(verts, faces, vecs, areas);
        long long nv = (long long)kB * kV;
        normalize_inplace_kernel<<<(int)((nv + 255) / 256), 256, 0, stream>>>(vecs);
    }
}

// Round 7
// 695.671 us; speedup vs baseline: 10.1079x; 1.1612x over previous
//
#include <hip/hip_runtime.h>
#include <hip/hip_fp16.h>
#include <math.h>

namespace {
constexpr int kB = 16;
constexpr int kV = 500000;
constexpr int kF = 1000000;
constexpr float kEps = 1e-6f;
constexpr int kNB = (kV + 255) / 256;     // 1954

// vtx16: [V] records of 32 uints (24 used = 48 fp16 comps, pad to 128 B line)
// fn16 : [F] records of 32 uints (24 used = 48 fp16 comps, pad to 128 B line)
constexpr size_t kVtx16Uints = (size_t)kV * 32;    // 64 MB
constexpr size_t kFn16Uints  = (size_t)kF * 32;    // 128 MB
constexpr size_t kIntBytes   = ((size_t)kV + (kV + 1) + kNB + 3 * (size_t)kF) * 4;
constexpr size_t kWs16 = (kVtx16Uints + kFn16Uints) * 4 + kIntBytes;  // ~208 MB
constexpr size_t kWsC  = kIntBytes;                                   // ~16 MB
}

// a*b - c*d unfused: degenerate faces cancel EXACTLY (matches numpy; the
// fp16-rounded coords of duplicate indices are identical, so e2 = -e1 and
// both products round identically). FMA contraction would leave ulp noise
// that normalization amplifies to O(1).
__device__ __forceinline__ float cross_comp(float a, float b, float c, float d) {
    return __fsub_rn(__fmul_rn(a, b), __fmul_rn(c, d));
}

__device__ __forceinline__ unsigned pack2(float a, float b) {
    __half2 h = __halves2half2(__float2half_rn(a), __float2half_rn(b));
    return __builtin_bit_cast(unsigned, h);
}
__device__ __forceinline__ float2 unpack2(unsigned u) {
    return __half22float2(__builtin_bit_cast(__half2, u));
}

// ---------- CSR build (bitwise-deterministic end state) ----------

__global__ __launch_bounds__(256) void zero_count_kernel(int* __restrict__ count) {
    int i = blockIdx.x * 256 + threadIdx.x;
    if (i < kV) count[i] = 0;
}

__global__ __launch_bounds__(256) void count_kernel(
    const int* __restrict__ faces, int* __restrict__ count)
{
    int i = blockIdx.x * 256 + threadIdx.x;
    if (i >= 3 * kF) return;
    atomicAdd(&count[faces[i]], 1);
}

__device__ __forceinline__ int block_incl_scan256(int x, int* lds) {
    int lane = threadIdx.x & 63;
    int wave = threadIdx.x >> 6;
    for (int d = 1; d < 64; d <<= 1) {
        int y = __shfl_up(x, d, 64);
        if (lane >= d) x += y;
    }
    if (lane == 63) lds[wave] = x;
    __syncthreads();
    int add = 0;
    for (int w = 0; w < wave; ++w) add += lds[w];
    __syncthreads();
    return x + add;
}

__global__ __launch_bounds__(256) void scan_block_kernel(
    const int* __restrict__ count, int* __restrict__ offs,
    int* __restrict__ blockSums)
{
    __shared__ int lds[4];
    int i = blockIdx.x * 256 + threadIdx.x;
    int x = (i < kV) ? count[i] : 0;
    int incl = block_incl_scan256(x, lds);
    if (i < kV) offs[i] = incl - x;
    if (threadIdx.x == 255) blockSums[blockIdx.x] = incl;
}

__global__ __launch_bounds__(256) void scan_sums_kernel(int* __restrict__ blockSums) {
    __shared__ int lds[4];
    __shared__ int carry;
    if (threadIdx.x == 0) carry = 0;
    __syncthreads();
    for (int base = 0; base < kNB; base += 256) {
        int i = base + threadIdx.x;
        int x = (i < kNB) ? blockSums[i] : 0;
        int incl = block_incl_scan256(x, lds);
        int c = carry;
        __syncthreads();
        if (i < kNB) blockSums[i] = incl - x + c;
        if (threadIdx.x == 255) carry = c + incl;
        __syncthreads();
    }
}

__global__ __launch_bounds__(256) void add_offsets_kernel(
    int* __restrict__ offs, const int* __restrict__ blockSums)
{
    int i = blockIdx.x * 256 + threadIdx.x;
    if (i < kV) offs[i] += blockSums[i >> 8];
    if (i == kV) offs[kV] = 3 * kF;
}

__global__ __launch_bounds__(256) void fill_adj_kernel(
    const int* __restrict__ faces, const int* __restrict__ offs,
    int* __restrict__ count, int* __restrict__ adj)
{
    int i = blockIdx.x * 256 + threadIdx.x;
    if (i >= 3 * kF) return;
    int v = faces[i];
    int f = i / 3;
    int old = atomicSub(&count[v], 1);
    adj[offs[v] + old - 1] = f;
}

// canonicalize slot order -> bitwise-deterministic adj -> deterministic fp sums
__global__ __launch_bounds__(256) void sort_rows_kernel(
    const int* __restrict__ offs, int* __restrict__ adj)
{
    int v = blockIdx.x * 256 + threadIdx.x;
    if (v >= kV) return;
    int s = offs[v], e = offs[v + 1];
    for (int i = s + 1; i < e; ++i) {
        int key = adj[i];
        int j = i - 1;
        while (j >= s && adj[j] > key) { adj[j + 1] = adj[j]; --j; }
        adj[j + 1] = key;
    }
}

// ---------- fp16-record path ----------

// verts [B][V][3] -> vtx16 [V][32u] (48 fp16 comps + pad; full 128 B written)
__global__ __launch_bounds__(256) void transpose_kernel16(
    const float* __restrict__ verts, unsigned* __restrict__ vtx16)
{
    int v = blockIdx.x * 256 + threadIdx.x;
    if (v >= kV) return;
    float o[48];
#pragma unroll
    for (int b = 0; b < kB; ++b) {
        const float* p = verts + ((size_t)b * kV + v) * 3;
        o[3 * b + 0] = p[0];
        o[3 * b + 1] = p[1];
        o[3 * b + 2] = p[2];
    }
    uint4* q = reinterpret_cast<uint4*>(vtx16 + (size_t)v * 32);
#pragma unroll
    for (int k = 0; k < 6; ++k)
        q[k] = make_uint4(pack2(o[8 * k + 0], o[8 * k + 1]),
                          pack2(o[8 * k + 2], o[8 * k + 3]),
                          pack2(o[8 * k + 4], o[8 * k + 5]),
                          pack2(o[8 * k + 6], o[8 * k + 7]));
    q[6] = make_uint4(0u, 0u, 0u, 0u);     // full-line write: no RFO
    q[7] = make_uint4(0u, 0u, 0u, 0u);
}

// Per face: 3 ONE-granule record gathers, 16 fp32 crosses from fp16 coords,
// areas (NT), fn16 record as a full 128 B line.
__global__ __launch_bounds__(256) void face_kernel16(
    const unsigned* __restrict__ vtx16, const int* __restrict__ faces,
    unsigned* __restrict__ fn16, float* __restrict__ areas)
{
    int f = blockIdx.x * 256 + threadIdx.x;
    if (f >= kF) return;
    int i0 = faces[3 * f + 0];
    int i1 = faces[3 * f + 1];
    int i2 = faces[3 * f + 2];
    const uint4* r0 = reinterpret_cast<const uint4*>(vtx16 + (size_t)i0 * 32);
    const uint4* r1 = reinterpret_cast<const uint4*>(vtx16 + (size_t)i1 * 32);
    const uint4* r2 = reinterpret_cast<const uint4*>(vtx16 + (size_t)i2 * 32);

    float o[48];
#pragma unroll
    for (int g = 0; g < 2; ++g) {          // 8 batches per group (VGPR control)
        // 3 uint4 per record per group = 24 fp16 comps
        float A[24], B[24], C[24];
#pragma unroll
        for (int k = 0; k < 3; ++k) {
            uint4 ua = r0[3 * g + k], ub = r1[3 * g + k], uc = r2[3 * g + k];
            float2 t;
            t = unpack2(ua.x); A[8 * k + 0] = t.x; A[8 * k + 1] = t.y;
            t = unpack2(ua.y); A[8 * k + 2] = t.x; A[8 * k + 3] = t.y;
            t = unpack2(ua.z); A[8 * k + 4] = t.x; A[8 * k + 5] = t.y;
            t = unpack2(ua.w); A[8 * k + 6] = t.x; A[8 * k + 7] = t.y;
            t = unpack2(ub.x); B[8 * k + 0] = t.x; B[8 * k + 1] = t.y;
            t = unpack2(ub.y); B[8 * k + 2] = t.x; B[8 * k + 3] = t.y;
            t = unpack2(ub.z); B[8 * k + 4] = t.x; B[8 * k + 5] = t.y;
            t = unpack2(ub.w); B[8 * k + 6] = t.x; B[8 * k + 7] = t.y;
            t = unpack2(uc.x); C[8 * k + 0] = t.x; C[8 * k + 1] = t.y;
            t = unpack2(uc.y); C[8 * k + 2] = t.x; C[8 * k + 3] = t.y;
            t = unpack2(uc.z); C[8 * k + 4] = t.x; C[8 * k + 5] = t.y;
            t = unpack2(uc.w); C[8 * k + 6] = t.x; C[8 * k + 7] = t.y;
        }
#pragma unroll
        for (int bb = 0; bb < 8; ++bb) {
            float x0 = A[3 * bb], y0 = A[3 * bb + 1], z0 = A[3 * bb + 2];
            float x1 = B[3 * bb], y1 = B[3 * bb + 1], z1 = B[3 * bb + 2];
            float x2 = C[3 * bb], y2 = C[3 * bb + 1], z2 = C[3 * bb + 2];
            float e1x = x1 - x0, e1y = y1 - y0, e1z = z1 - z0;
            float e2x = x2 - x1, e2y = y2 - y1, e2z = z2 - z1;
            float nx = cross_comp(e1y, e2z, e1z, e2y);
            float ny = cross_comp(e1z, e2x, e1x, e2z);
            float nz = cross_comp(e1x, e2y, e1y, e2x);
            int bi = 8 * g + bb;
            o[3 * bi + 0] = nx;
            o[3 * bi + 1] = ny;
            o[3 * bi + 2] = nz;
            __builtin_nontemporal_store(
                0.5f * sqrtf(nx * nx + ny * ny + nz * nz),
                &areas[(size_t)bi * kF + f]);
        }
    }
    uint4* q = reinterpret_cast<uint4*>(fn16 + (size_t)f * 32);
#pragma unroll
    for (int k = 0; k < 6; ++k)
        q[k] = make_uint4(pack2(o[8 * k + 0], o[8 * k + 1]),
                          pack2(o[8 * k + 2], o[8 * k + 3]),
                          pack2(o[8 * k + 4], o[8 * k + 5]),
                          pack2(o[8 * k + 6], o[8 * k + 7]));
    q[6] = make_uint4(0u, 0u, 0u, 0u);     // full-line write: no RFO
    q[7] = make_uint4(0u, 0u, 0u, 0u);
}

// Per vertex: walk sorted CSR, ONE-granule fn16 gathers (all 16 batches),
// fp32 accumulate, normalize, NT store.
__global__ __launch_bounds__(256) void vertex_kernel16(
    const unsigned* __restrict__ fn16, const int* __restrict__ offs,
    const int* __restrict__ adj, float* __restrict__ out)
{
    int v = blockIdx.x * 256 + threadIdx.x;
    if (v >= kV) return;
    int s = offs[v], e = offs[v + 1];

    float acc[48];
#pragma unroll
    for (int i = 0; i < 48; ++i) acc[i] = 0.f;

    for (int j = s; j < e; ++j) {
        const uint4* q = reinterpret_cast<const uint4*>(fn16 + (size_t)adj[j] * 32);
        uint4 w[6];
#pragma unroll
        for (int k = 0; k < 6; ++k) w[k] = q[k];
#pragma unroll
        for (int k = 0; k < 6; ++k) {
            float2 t0 = unpack2(w[k].x), t1 = unpack2(w[k].y);
            float2 t2 = unpack2(w[k].z), t3 = unpack2(w[k].w);
            acc[8 * k + 0] += t0.x; acc[8 * k + 1] += t0.y;
            acc[8 * k + 2] += t1.x; acc[8 * k + 3] += t1.y;
            acc[8 * k + 4] += t2.x; acc[8 * k + 5] += t2.y;
            acc[8 * k + 6] += t3.x; acc[8 * k + 7] += t3.y;
        }
    }

#pragma unroll
    for (int bi = 0; bi < kB; ++bi) {
        float x = acc[3 * bi], y = acc[3 * bi + 1], z = acc[3 * bi + 2];
        float n = sqrtf(x * x + y * y + z * z);
        float inv = 1.0f / fmaxf(n, kEps);
        size_t o = ((size_t)bi * kV + v) * 3;
        __builtin_nontemporal_store(x * inv, &out[o + 0]);
        __builtin_nontemporal_store(y * inv, &out[o + 1]);
        __builtin_nontemporal_store(z * inv, &out[o + 2]);
    }
}

// ---------- R3 fallback (ws >= 16 MB) ----------

__global__ __launch_bounds__(256) void area_kernel_orig(
    const float* __restrict__ verts, const int* __restrict__ faces,
    float* __restrict__ areas)
{
    int f = blockIdx.x * 256 + threadIdx.x;
    if (f >= kF) return;
    int i0 = faces[3 * f + 0];
    int i1 = faces[3 * f + 1];
    int i2 = faces[3 * f + 2];
    size_t o0 = 3 * (size_t)i0, o1 = 3 * (size_t)i1, o2 = 3 * (size_t)i2;
#pragma unroll
    for (int b = 0; b < kB; ++b) {
        const float* vb = verts + (size_t)b * kV * 3;
        float x0 = vb[o0], y0 = vb[o0 + 1], z0 = vb[o0 + 2];
        float x1 = vb[o1], y1 = vb[o1 + 1], z1 = vb[o1 + 2];
        float x2 = vb[o2], y2 = vb[o2 + 1], z2 = vb[o2 + 2];
        float e1x = x1 - x0, e1y = y1 - y0, e1z = z1 - z0;
        float e2x = x2 - x1, e2y = y2 - y1, e2z = z2 - z1;
        float nx = cross_comp(e1y, e2z, e1z, e2y);
        float ny = cross_comp(e1z, e2x, e1x, e2z);
        float nz = cross_comp(e1x, e2y, e1y, e2x);
        areas[(size_t)b * kF + f] = 0.5f * sqrtf(nx * nx + ny * ny + nz * nz);
    }
}

__global__ __launch_bounds__(256) void gather_normalize_orig(
    const float* __restrict__ verts, const int* __restrict__ faces,
    const int* __restrict__ offs, const int* __restrict__ adj,
    float* __restrict__ out)
{
    int v = blockIdx.x * 256 + threadIdx.x;
    if (v >= kV) return;
    int s = offs[v], e = offs[v + 1];
    float ax[kB], ay[kB], az[kB];
#pragma unroll
    for (int b = 0; b < kB; ++b) { ax[b] = 0.f; ay[b] = 0.f; az[b] = 0.f; }
    for (int j = s; j < e; ++j) {
        int f = adj[j];
        int i0 = faces[3 * f + 0];
        int i1 = faces[3 * f + 1];
        int i2 = faces[3 * f + 2];
        size_t o0 = 3 * (size_t)i0, o1 = 3 * (size_t)i1, o2 = 3 * (size_t)i2;
#pragma unroll
        for (int b = 0; b < kB; ++b) {
            const float* vb = verts + (size_t)b * kV * 3;
            float x0 = vb[o0], y0 = vb[o0 + 1], z0 = vb[o0 + 2];
            float x1 = vb[o1], y1 = vb[o1 + 1], z1 = vb[o1 + 2];
            float x2 = vb[o2], y2 = vb[o2 + 1], z2 = vb[o2 + 2];
            float e1x = x1 - x0, e1y = y1 - y0, e1z = z1 - z0;
            float e2x = x2 - x1, e2y = y2 - y1, e2z = z2 - z1;
            ax[b] += cross_comp(e1y, e2z, e1z, e2y);
            ay[b] += cross_comp(e1z, e2x, e1x, e2z);
            az[b] += cross_comp(e1x, e2y, e1y, e2x);
        }
    }
#pragma unroll
    for (int b = 0; b < kB; ++b) {
        float n = sqrtf(ax[b] * ax[b] + ay[b] * ay[b] + az[b] * az[b]);
        float inv = 1.0f / fmaxf(n, kEps);
        size_t o = ((size_t)b * kV + v) * 3;
        out[o + 0] = ax[b] * inv;
        out[o + 1] = ay[b] * inv;
        out[o + 2] = az[b] * inv;
    }
}

// ---------- R1 fallback ----------

__global__ __launch_bounds__(256) void face_normals_atomic_kernel(
    const float* __restrict__ verts, const int* __restrict__ faces,
    float* __restrict__ vnorm, float* __restrict__ areas)
{
    long long tid = (long long)blockIdx.x * blockDim.x + threadIdx.x;
    if (tid >= (long long)kB * kF) return;
    int f = (int)(tid % kF);
    int b = (int)(tid / kF);
    int i0 = faces[3 * f + 0], i1 = faces[3 * f + 1], i2 = faces[3 * f + 2];
    const float* vb = verts + (size_t)b * kV * 3;
    size_t o0 = 3 * (size_t)i0, o1 = 3 * (size_t)i1, o2 = 3 * (size_t)i2;
    float x0 = vb[o0], y0 = vb[o0 + 1], z0 = vb[o0 + 2];
    float x1 = vb[o1], y1 = vb[o1 + 1], z1 = vb[o1 + 2];
    float x2 = vb[o2], y2 = vb[o2 + 1], z2 = vb[o2 + 2];
    float e1x = x1 - x0, e1y = y1 - y0, e1z = z1 - z0;
    float e2x = x2 - x1, e2y = y2 - y1, e2z = z2 - z1;
    float nx = cross_comp(e1y, e2z, e1z, e2y);
    float ny = cross_comp(e1z, e2x, e1x, e2z);
    float nz = cross_comp(e1x, e2y, e1y, e2x);
    float* vn = vnorm + (size_t)b * kV * 3;
    unsafeAtomicAdd(&vn[o0 + 0], nx); unsafeAtomicAdd(&vn[o0 + 1], ny); unsafeAtomicAdd(&vn[o0 + 2], nz);
    unsafeAtomicAdd(&vn[o1 + 0], nx); unsafeAtomicAdd(&vn[o1 + 1], ny); unsafeAtomicAdd(&vn[o1 + 2], nz);
    unsafeAtomicAdd(&vn[o2 + 0], nx); unsafeAtomicAdd(&vn[o2 + 1], ny); unsafeAtomicAdd(&vn[o2 + 2], nz);
    areas[(size_t)b * kF + f] = 0.5f * sqrtf(nx * nx + ny * ny + nz * nz);
}

__global__ __launch_bounds__(256) void normalize_inplace_kernel(float* __restrict__ vnorm) {
    long long tid = (long long)blockIdx.x * blockDim.x + threadIdx.x;
    if (tid >= (long long)kB * kV) return;
    size_t o = 3 * (size_t)tid;
    float x = vnorm[o], y = vnorm[o + 1], z = vnorm[o + 2];
    float n = sqrtf(x * x + y * y + z * z);
    float inv = 1.0f / fmaxf(n, kEps);
    vnorm[o] = x * inv; vnorm[o + 1] = y * inv; vnorm[o + 2] = z * inv;
}

// ---------- launch ----------

static void build_csr(const int* faces, int* count, int* offs, int* blockSums,
                      int* adj, hipStream_t stream) {
    int gInc = (3 * kF + 255) / 256;
    zero_count_kernel<<<kNB, 256, 0, stream>>>(count);
    count_kernel<<<gInc, 256, 0, stream>>>(faces, count);
    scan_block_kernel<<<kNB, 256, 0, stream>>>(count, offs, blockSums);
    scan_sums_kernel<<<1, 256, 0, stream>>>(blockSums);
    add_offsets_kernel<<<(kV + 1 + 255) / 256, 256, 0, stream>>>(offs, blockSums);
    fill_adj_kernel<<<gInc, 256, 0, stream>>>(faces, offs, count, adj);
    sort_rows_kernel<<<kNB, 256, 0, stream>>>(offs, adj);
}

extern "C" void kernel_launch(void* const* d_in, const int* in_sizes, int n_in,
                              void* d_out, int out_size, void* d_ws, size_t ws_size,
                              hipStream_t stream) {
    const float* verts = (const float*)d_in[0];
    const int*   faces = (const int*)d_in[1];

    float* out   = (float*)d_out;
    float* vecs  = out;                               // B*V*3
    float* areas = out + (size_t)kB * kV * 3;         // B*F

    int gF = (kF + 255) / 256;

    if (ws_size >= kWs16) {
        unsigned* vtx16 = (unsigned*)d_ws;                    // 64 MB
        unsigned* fn16  = vtx16 + kVtx16Uints;                // 128 MB
        int* count     = (int*)(fn16 + kFn16Uints);
        int* offs      = count + kV;
        int* blockSums = offs + (kV + 1);
        int* adj       = blockSums + kNB;

        build_csr(faces, count, offs, blockSums, adj, stream);
        transpose_kernel16<<<kNB, 256, 0, stream>>>(verts, vtx16);
        face_kernel16<<<gF, 256, 0, stream>>>(vtx16, faces, fn16, areas);
        vertex_kernel16<<<kNB, 256, 0, stream>>>(fn16, offs, adj, vecs);
    } else if (ws_size >= kWsC) {
        int* count     = (int*)d_ws;
        int* offs      = count + kV;
        int* blockSums = offs + (kV + 1);
        int* adj       = blockSums + kNB;

        build_csr(faces, count, offs, blockSums, adj, stream);
        area_kernel_orig<<<gF, 256, 0, stream>>>(verts, faces, areas);
        gather_normalize_orig<<<kNB, 256, 0, stream>>>(verts, faces, offs, adj, vecs);
    } else {
        hipMemsetAsync(vecs, 0, (size_t)kB * kV * 3 * sizeof(float), stream);
        long long nf = (long long)kB * kF;
        face_normals_atomic_kernel<<<(int)((nf + 255) / 256), 256, 0, stream>>>(verts, faces, vecs, areas);
        long long nv = (long long)kB * kV;
        normalize_inplace_kernel<<<(int)((nv + 255) / 256), 256, 0, stream>>>(vecs);
    }
}

// Round 9
// 584.428 us; speedup vs baseline: 12.0319x; 1.1903x over previous
//
#include <hip/hip_runtime.h>
#include <hip/hip_fp16.h>
#include <math.h>

namespace {
constexpr int kB = 16;
constexpr int kV = 500000;
constexpr int kF = 1000000;
constexpr float kEps = 1e-6f;
constexpr int kNB = (kV + 255) / 256;     // 1954

// vtx16: [V] records of 32 uints (24 used = 48 fp16 comps, pad to 128 B line)
// fn16 : [F] records of 32 uints (24 used = 48 fp16 comps, pad to 128 B line)
constexpr size_t kVtx16Uints = (size_t)kV * 32;    // 64 MB
constexpr size_t kFn16Uints  = (size_t)kF * 32;    // 128 MB
constexpr size_t kIntBytes   = ((size_t)kV + (kV + 1) + kNB + 3 * (size_t)kF) * 4;
constexpr size_t kWs16 = (kVtx16Uints + kFn16Uints) * 4 + kIntBytes;  // ~208 MB
constexpr size_t kWsC  = kIntBytes;                                   // ~16 MB
}

// a*b - c*d unfused: degenerate faces cancel EXACTLY (matches numpy; the
// fp16-rounded coords of duplicate indices are identical, so e2 = -e1 and
// both products round identically). FMA contraction would leave ulp noise
// that normalization amplifies to O(1).
__device__ __forceinline__ float cross_comp(float a, float b, float c, float d) {
    return __fsub_rn(__fmul_rn(a, b), __fmul_rn(c, d));
}

__device__ __forceinline__ unsigned pack2(float a, float b) {
    __half2 h = __halves2half2(__float2half_rn(a), __float2half_rn(b));
    return __builtin_bit_cast(unsigned, h);
}
__device__ __forceinline__ float2 unpack2(unsigned u) {
    return __half22float2(__builtin_bit_cast(__half2, u));
}

// Stage 64 records/wave (8 KB) in LDS, then write out so every store
// instruction covers 8 FULL 128 B lines (1 KB contiguous per wave per
// iteration) -> no read-for-ownership / write-allocate fetches. The tables
// are re-read by later kernels, so plain (cached) stores are correct here.
// lds layout: [wave][record][slot], slot rotated by record for bank spread.
__device__ __forceinline__ void staged_record_write(
    uint4 lds[4][64][8], const uint4 q[8], uint4* __restrict__ dstBase,
    size_t baseRec, int maxRec, int wave, int lane)
{
#pragma unroll
    for (int k = 0; k < 8; ++k)
        lds[wave][lane][(k + lane) & 7] = q[k];
    __syncthreads();
    uint4* dst = dstBase + baseRec * 8;
#pragma unroll
    for (int k = 0; k < 8; ++k) {
        int g = k * 64 + lane;          // uint4 index within wave's 8 KB
        int r = g >> 3, w = g & 7;
        if (baseRec + (size_t)r < (size_t)maxRec)
            dst[g] = lds[wave][r][(w + r) & 7];
    }
}

// ---------- CSR build (bitwise-deterministic end state) ----------

__global__ __launch_bounds__(256) void zero_count_kernel(int* __restrict__ count) {
    int i = blockIdx.x * 256 + threadIdx.x;
    if (i < kV) count[i] = 0;
}

__global__ __launch_bounds__(256) void count_kernel(
    const int* __restrict__ faces, int* __restrict__ count)
{
    int i = blockIdx.x * 256 + threadIdx.x;
    if (i >= 3 * kF) return;
    atomicAdd(&count[faces[i]], 1);
}

__device__ __forceinline__ int block_incl_scan256(int x, int* lds) {
    int lane = threadIdx.x & 63;
    int wave = threadIdx.x >> 6;
    for (int d = 1; d < 64; d <<= 1) {
        int y = __shfl_up(x, d, 64);
        if (lane >= d) x += y;
    }
    if (lane == 63) lds[wave] = x;
    __syncthreads();
    int add = 0;
    for (int w = 0; w < wave; ++w) add += lds[w];
    __syncthreads();
    return x + add;
}

__global__ __launch_bounds__(256) void scan_block_kernel(
    const int* __restrict__ count, int* __restrict__ offs,
    int* __restrict__ blockSums)
{
    __shared__ int lds[4];
    int i = blockIdx.x * 256 + threadIdx.x;
    int x = (i < kV) ? count[i] : 0;
    int incl = block_incl_scan256(x, lds);
    if (i < kV) offs[i] = incl - x;
    if (threadIdx.x == 255) blockSums[blockIdx.x] = incl;
}

__global__ __launch_bounds__(256) void scan_sums_kernel(int* __restrict__ blockSums) {
    __shared__ int lds[4];
    __shared__ int carry;
    if (threadIdx.x == 0) carry = 0;
    __syncthreads();
    for (int base = 0; base < kNB; base += 256) {
        int i = base + threadIdx.x;
        int x = (i < kNB) ? blockSums[i] : 0;
        int incl = block_incl_scan256(x, lds);
        int c = carry;
        __syncthreads();
        if (i < kNB) blockSums[i] = incl - x + c;
        if (threadIdx.x == 255) carry = c + incl;
        __syncthreads();
    }
}

__global__ __launch_bounds__(256) void add_offsets_kernel(
    int* __restrict__ offs, const int* __restrict__ blockSums)
{
    int i = blockIdx.x * 256 + threadIdx.x;
    if (i < kV) offs[i] += blockSums[i >> 8];
    if (i == kV) offs[kV] = 3 * kF;
}

__global__ __launch_bounds__(256) void fill_adj_kernel(
    const int* __restrict__ faces, const int* __restrict__ offs,
    int* __restrict__ count, int* __restrict__ adj)
{
    int i = blockIdx.x * 256 + threadIdx.x;
    if (i >= 3 * kF) return;
    int v = faces[i];
    int f = i / 3;
    int old = atomicSub(&count[v], 1);
    adj[offs[v] + old - 1] = f;
}

// canonicalize slot order -> bitwise-deterministic adj -> deterministic fp sums
__global__ __launch_bounds__(256) void sort_rows_kernel(
    const int* __restrict__ offs, int* __restrict__ adj)
{
    int v = blockIdx.x * 256 + threadIdx.x;
    if (v >= kV) return;
    int s = offs[v], e = offs[v + 1];
    for (int i = s + 1; i < e; ++i) {
        int key = adj[i];
        int j = i - 1;
        while (j >= s && adj[j] > key) { adj[j + 1] = adj[j]; --j; }
        adj[j + 1] = key;
    }
}

// ---------- fp16-record path ----------

// verts [B][V][3] -> vtx16 [V][32u]; staged full-line writes (no RFO).
__global__ __launch_bounds__(256) void transpose_kernel16(
    const float* __restrict__ verts, unsigned* __restrict__ vtx16)
{
    __shared__ uint4 lds[4][64][8];
    int tid = threadIdx.x;
    int wave = tid >> 6, lane = tid & 63;
    int v = blockIdx.x * 256 + tid;
    bool valid = v < kV;

    float o[48];
#pragma unroll
    for (int i = 0; i < 48; ++i) o[i] = 0.f;
    if (valid) {
#pragma unroll
        for (int b = 0; b < kB; ++b) {
            const float* p = verts + ((size_t)b * kV + v) * 3;
            o[3 * b + 0] = p[0];
            o[3 * b + 1] = p[1];
            o[3 * b + 2] = p[2];
        }
    }
    uint4 q[8];
#pragma unroll
    for (int k = 0; k < 6; ++k)
        q[k] = make_uint4(pack2(o[8 * k + 0], o[8 * k + 1]),
                          pack2(o[8 * k + 2], o[8 * k + 3]),
                          pack2(o[8 * k + 4], o[8 * k + 5]),
                          pack2(o[8 * k + 6], o[8 * k + 7]));
    q[6] = make_uint4(0u, 0u, 0u, 0u);
    q[7] = make_uint4(0u, 0u, 0u, 0u);

    size_t baseRec = (size_t)blockIdx.x * 256 + wave * 64;
    staged_record_write(lds, q, reinterpret_cast<uint4*>(vtx16),
                        baseRec, kV, wave, lane);
}

// Per face: 3 ONE-granule record gathers, 16 fp32 crosses from fp16 coords,
// areas (coalesced full lines, NT), fn16 via staged full-line writes.
__global__ __launch_bounds__(256) void face_kernel16(
    const unsigned* __restrict__ vtx16, const int* __restrict__ faces,
    unsigned* __restrict__ fn16, float* __restrict__ areas)
{
    __shared__ uint4 lds[4][64][8];
    int tid = threadIdx.x;
    int wave = tid >> 6, lane = tid & 63;
    int f = blockIdx.x * 256 + tid;
    bool valid = f < kF;

    float o[48];
#pragma unroll
    for (int i = 0; i < 48; ++i) o[i] = 0.f;

    if (valid) {
        int i0 = faces[3 * f + 0];
        int i1 = faces[3 * f + 1];
        int i2 = faces[3 * f + 2];
        const uint4* r0 = reinterpret_cast<const uint4*>(vtx16 + (size_t)i0 * 32);
        const uint4* r1 = reinterpret_cast<const uint4*>(vtx16 + (size_t)i1 * 32);
        const uint4* r2 = reinterpret_cast<const uint4*>(vtx16 + (size_t)i2 * 32);
#pragma unroll
        for (int g = 0; g < 2; ++g) {      // 8 batches per group (VGPR control)
            float A[24], B[24], C[24];
#pragma unroll
            for (int k = 0; k < 3; ++k) {
                uint4 ua = r0[3 * g + k], ub = r1[3 * g + k], uc = r2[3 * g + k];
                float2 t;
                t = unpack2(ua.x); A[8 * k + 0] = t.x; A[8 * k + 1] = t.y;
                t = unpack2(ua.y); A[8 * k + 2] = t.x; A[8 * k + 3] = t.y;
                t = unpack2(ua.z); A[8 * k + 4] = t.x; A[8 * k + 5] = t.y;
                t = unpack2(ua.w); A[8 * k + 6] = t.x; A[8 * k + 7] = t.y;
                t = unpack2(ub.x); B[8 * k + 0] = t.x; B[8 * k + 1] = t.y;
                t = unpack2(ub.y); B[8 * k + 2] = t.x; B[8 * k + 3] = t.y;
                t = unpack2(ub.z); B[8 * k + 4] = t.x; B[8 * k + 5] = t.y;
                t = unpack2(ub.w); B[8 * k + 6] = t.x; B[8 * k + 7] = t.y;
                t = unpack2(uc.x); C[8 * k + 0] = t.x; C[8 * k + 1] = t.y;
                t = unpack2(uc.y); C[8 * k + 2] = t.x; C[8 * k + 3] = t.y;
                t = unpack2(uc.z); C[8 * k + 4] = t.x; C[8 * k + 5] = t.y;
                t = unpack2(uc.w); C[8 * k + 6] = t.x; C[8 * k + 7] = t.y;
            }
#pragma unroll
            for (int bb = 0; bb < 8; ++bb) {
                float x0 = A[3 * bb], y0 = A[3 * bb + 1], z0 = A[3 * bb + 2];
                float x1 = B[3 * bb], y1 = B[3 * bb + 1], z1 = B[3 * bb + 2];
                float x2 = C[3 * bb], y2 = C[3 * bb + 1], z2 = C[3 * bb + 2];
                float e1x = x1 - x0, e1y = y1 - y0, e1z = z1 - z0;
                float e2x = x2 - x1, e2y = y2 - y1, e2z = z2 - z1;
                float nx = cross_comp(e1y, e2z, e1z, e2y);
                float ny = cross_comp(e1z, e2x, e1x, e2z);
                float nz = cross_comp(e1x, e2y, e1y, e2x);
                int bi = 8 * g + bb;
                o[3 * bi + 0] = nx;
                o[3 * bi + 1] = ny;
                o[3 * bi + 2] = nz;
                // wave writes 256 B contiguous per bi -> full lines, no RFO
                __builtin_nontemporal_store(
                    0.5f * sqrtf(nx * nx + ny * ny + nz * nz),
                    &areas[(size_t)bi * kF + f]);
            }
        }
    }

    uint4 q[8];
#pragma unroll
    for (int k = 0; k < 6; ++k)
        q[k] = make_uint4(pack2(o[8 * k + 0], o[8 * k + 1]),
                          pack2(o[8 * k + 2], o[8 * k + 3]),
                          pack2(o[8 * k + 4], o[8 * k + 5]),
                          pack2(o[8 * k + 6], o[8 * k + 7]));
    q[6] = make_uint4(0u, 0u, 0u, 0u);
    q[7] = make_uint4(0u, 0u, 0u, 0u);

    size_t baseRec = (size_t)blockIdx.x * 256 + wave * 64;
    staged_record_write(lds, q, reinterpret_cast<uint4*>(fn16),
                        baseRec, kF, wave, lane);
}

// Per vertex: walk sorted CSR, ONE-granule fn16 gathers (all 16 batches),
// fp32 accumulate, normalize, NT store.
__global__ __launch_bounds__(256) void vertex_kernel16(
    const unsigned* __restrict__ fn16, const int* __restrict__ offs,
    const int* __restrict__ adj, float* __restrict__ out)
{
    int v = blockIdx.x * 256 + threadIdx.x;
    if (v >= kV) return;
    int s = offs[v], e = offs[v + 1];

    float acc[48];
#pragma unroll
    for (int i = 0; i < 48; ++i) acc[i] = 0.f;

    for (int j = s; j < e; ++j) {
        const uint4* q = reinterpret_cast<const uint4*>(fn16 + (size_t)adj[j] * 32);
        uint4 w[6];
#pragma unroll
        for (int k = 0; k < 6; ++k) w[k] = q[k];
#pragma unroll
        for (int k = 0; k < 6; ++k) {
            float2 t0 = unpack2(w[k].x), t1 = unpack2(w[k].y);
            float2 t2 = unpack2(w[k].z), t3 = unpack2(w[k].w);
            acc[8 * k + 0] += t0.x; acc[8 * k + 1] += t0.y;
            acc[8 * k + 2] += t1.x; acc[8 * k + 3] += t1.y;
            acc[8 * k + 4] += t2.x; acc[8 * k + 5] += t2.y;
            acc[8 * k + 6] += t3.x; acc[8 * k + 7] += t3.y;
        }
    }

#pragma unroll
    for (int bi = 0; bi < kB; ++bi) {
        float x = acc[3 * bi], y = acc[3 * bi + 1], z = acc[3 * bi + 2];
        float n = sqrtf(x * x + y * y + z * z);
        float inv = 1.0f / fmaxf(n, kEps);
        size_t o = ((size_t)bi * kV + v) * 3;
        __builtin_nontemporal_store(x * inv, &out[o + 0]);
        __builtin_nontemporal_store(y * inv, &out[o + 1]);
        __builtin_nontemporal_store(z * inv, &out[o + 2]);
    }
}

// ---------- R3 fallback (ws >= 16 MB) ----------

__global__ __launch_bounds__(256) void area_kernel_orig(
    const float* __restrict__ verts, const int* __restrict__ faces,
    float* __restrict__ areas)
{
    int f = blockIdx.x * 256 + threadIdx.x;
    if (f >= kF) return;
    int i0 = faces[3 * f + 0];
    int i1 = faces[3 * f + 1];
    int i2 = faces[3 * f + 2];
    size_t o0 = 3 * (size_t)i0, o1 = 3 * (size_t)i1, o2 = 3 * (size_t)i2;
#pragma unroll
    for (int b = 0; b < kB; ++b) {
        const float* vb = verts + (size_t)b * kV * 3;
        float x0 = vb[o0], y0 = vb[o0 + 1], z0 = vb[o0 + 2];
        float x1 = vb[o1], y1 = vb[o1 + 1], z1 = vb[o1 + 2];
        float x2 = vb[o2], y2 = vb[o2 + 1], z2 = vb[o2 + 2];
        float e1x = x1 - x0, e1y = y1 - y0, e1z = z1 - z0;
        float e2x = x2 - x1, e2y = y2 - y1, e2z = z2 - z1;
        float nx = cross_comp(e1y, e2z, e1z, e2y);
        float ny = cross_comp(e1z, e2x, e1x, e2z);
        float nz = cross_comp(e1x, e2y, e1y, e2x);
        areas[(size_t)b * kF + f] = 0.5f * sqrtf(nx * nx + ny * ny + nz * nz);
    }
}

__global__ __launch_bounds__(256) void gather_normalize_orig(
    const float* __restrict__ verts, const int* __restrict__ faces,
    const int* __restrict__ offs, const int* __restrict__ adj,
    float* __restrict__ out)
{
    int v = blockIdx.x * 256 + threadIdx.x;
    if (v >= kV) return;
    int s = offs[v], e = offs[v + 1];
    float ax[kB], ay[kB], az[kB];
#pragma unroll
    for (int b = 0; b < kB; ++b) { ax[b] = 0.f; ay[b] = 0.f; az[b] = 0.f; }
    for (int j = s; j < e; ++j) {
        int f = adj[j];
        int i0 = faces[3 * f + 0];
        int i1 = faces[3 * f + 1];
        int i2 = faces[3 * f + 2];
        size_t o0 = 3 * (size_t)i0, o1 = 3 * (size_t)i1, o2 = 3 * (size_t)i2;
#pragma unroll
        for (int b = 0; b < kB; ++b) {
            const float* vb = verts + (size_t)b * kV * 3;
            float x0 = vb[o0], y0 = vb[o0 + 1], z0 = vb[o0 + 2];
            float x1 = vb[o1], y1 = vb[o1 + 1], z1 = vb[o1 + 2];
            float x2 = vb[o2], y2 = vb[o2 + 1], z2 = vb[o2 + 2];
            float e1x = x1 - x0, e1y = y1 - y0, e1z = z1 - z0;
            float e2x = x2 - x1, e2y = y2 - y1, e2z = z2 - z1;
            ax[b] += cross_comp(e1y, e2z, e1z, e2y);
            ay[b] += cross_comp(e1z, e2x, e1x, e2z);
            az[b] += cross_comp(e1x, e2y, e1y, e2x);
        }
    }
#pragma unroll
    for (int b = 0; b < kB; ++b) {
        float n = sqrtf(ax[b] * ax[b] + ay[b] * ay[b] + az[b] * az[b]);
        float inv = 1.0f / fmaxf(n, kEps);
        size_t o = ((size_t)b * kV + v) * 3;
        out[o + 0] = ax[b] * inv;
        out[o + 1] = ay[b] * inv;
        out[o + 2] = az[b] * inv;
    }
}

// ---------- R1 fallback ----------

__global__ __launch_bounds__(256) void face_normals_atomic_kernel(
    const float* __restrict__ verts, const int* __restrict__ faces,
    float* __restrict__ vnorm, float* __restrict__ areas)
{
    long long tid = (long long)blockIdx.x * blockDim.x + threadIdx.x;
    if (tid >= (long long)kB * kF) return;
    int f = (int)(tid % kF);
    int b = (int)(tid / kF);
    int i0 = faces[3 * f + 0], i1 = faces[3 * f + 1], i2 = faces[3 * f + 2];
    const float* vb = verts + (size_t)b * kV * 3;
    size_t o0 = 3 * (size_t)i0, o1 = 3 * (size_t)i1, o2 = 3 * (size_t)i2;
    float x0 = vb[o0], y0 = vb[o0 + 1], z0 = vb[o0 + 2];
    float x1 = vb[o1], y1 = vb[o1 + 1], z1 = vb[o1 + 2];
    float x2 = vb[o2], y2 = vb[o2 + 1], z2 = vb[o2 + 2];
    float e1x = x1 - x0, e1y = y1 - y0, e1z = z1 - z0;
    float e2x = x2 - x1, e2y = y2 - y1, e2z = z2 - z1;
    float nx = cross_comp(e1y, e2z, e1z, e2y);
    float ny = cross_comp(e1z, e2x, e1x, e2z);
    float nz = cross_comp(e1x, e2y, e1y, e2x);
    float* vn = vnorm + (size_t)b * kV * 3;
    unsafeAtomicAdd(&vn[o0 + 0], nx); unsafeAtomicAdd(&vn[o0 + 1], ny); unsafeAtomicAdd(&vn[o0 + 2], nz);
    unsafeAtomicAdd(&vn[o1 + 0], nx); unsafeAtomicAdd(&vn[o1 + 1], ny); unsafeAtomicAdd(&vn[o1 + 2], nz);
    unsafeAtomicAdd(&vn[o2 + 0], nx); unsafeAtomicAdd(&vn[o2 + 1], ny); unsafeAtomicAdd(&vn[o2 + 2], nz);
    areas[(size_t)b * kF + f] = 0.5f * sqrtf(nx * nx + ny * ny + nz * nz);
}

__global__ __launch_bounds__(256) void normalize_inplace_kernel(float* __restrict__ vnorm) {
    long long tid = (long long)blockIdx.x * blockDim.x + threadIdx.x;
    if (tid >= (long long)kB * kV) return;
    size_t o = 3 * (size_t)tid;
    float x = vnorm[o], y = vnorm[o + 1], z = vnorm[o + 2];
    float n = sqrtf(x * x + y * y + z * z);
    float inv = 1.0f / fmaxf(n, kEps);
    vnorm[o] = x * inv; vnorm[o + 1] = y * inv; vnorm[o + 2] = z * inv;
}

// ---------- launch ----------

static void build_csr(const int* faces, int* count, int* offs, int* blockSums,
                      int* adj, hipStream_t stream) {
    int gInc = (3 * kF + 255) / 256;
    zero_count_kernel<<<kNB, 256, 0, stream>>>(count);
    count_kernel<<<gInc, 256, 0, stream>>>(faces, count);
    scan_block_kernel<<<kNB, 256, 0, stream>>>(count, offs, blockSums);
    scan_sums_kernel<<<1, 256, 0, stream>>>(blockSums);
    add_offsets_kernel<<<(kV + 1 + 255) / 256, 256, 0, stream>>>(offs, blockSums);
    fill_adj_kernel<<<gInc, 256, 0, stream>>>(faces, offs, count, adj);
    sort_rows_kernel<<<kNB, 256, 0, stream>>>(offs, adj);
}

extern "C" void kernel_launch(void* const* d_in, const int* in_sizes, int n_in,
                              void* d_out, int out_size, void* d_ws, size_t ws_size,
                              hipStream_t stream) {
    const float* verts = (const float*)d_in[0];
    const int*   faces = (const int*)d_in[1];

    float* out   = (float*)d_out;
    float* vecs  = out;                               // B*V*3
    float* areas = out + (size_t)kB * kV * 3;         // B*F

    int gF = (kF + 255) / 256;

    if (ws_size >= kWs16) {
        unsigned* vtx16 = (unsigned*)d_ws;                    // 64 MB
        unsigned* fn16  = vtx16 + kVtx16Uints;                // 128 MB
        int* count     = (int*)(fn16 + kFn16Uints);
        int* offs      = count + kV;
        int* blockSums = offs + (kV + 1);
        int* adj       = blockSums + kNB;

        build_csr(faces, count, offs, blockSums, adj, stream);
        transpose_kernel16<<<kNB, 256, 0, stream>>>(verts, vtx16);
        face_kernel16<<<gF, 256, 0, stream>>>(vtx16, faces, fn16, areas);
        vertex_kernel16<<<kNB, 256, 0, stream>>>(fn16, offs, adj, vecs);
    } else if (ws_size >= kWsC) {
        int* count     = (int*)d_ws;
        int* offs      = count + kV;
        int* blockSums = offs + (kV + 1);
        int* adj       = blockSums + kNB;

        build_csr(faces, count, offs, blockSums, adj, stream);
        area_kernel_orig<<<gF, 256, 0, stream>>>(verts, faces, areas);
        gather_normalize_orig<<<kNB, 256, 0, stream>>>(verts, faces, offs, adj, vecs);
    } else {
        (void)hipMemsetAsync(vecs, 0, (size_t)kB * kV * 3 * sizeof(float), stream);
        long long nf = (long long)kB * kF;
        face_normals_atomic_kernel<<<(int)((nf + 255) / 256), 256, 0, stream>>>(verts, faces, vecs, areas);
        long long nv = (long long)kB * kV;
        normalize_inplace_kernel<<<(int)((nv + 255) / 256), 256, 0, stream>>>(vecs);
    }
}